// Round 8
// baseline (818.393 us; speedup 1.0000x reference)
//
#include <hip/hip_runtime.h>

#define D 128            // hidden dim
#define DOUT 10
#define CT_STRIDE 152    // C-tile LDS row stride in u16 (304 B: 16B-aligned, banks spread)

typedef float f32x4 __attribute__((ext_vector_type(4)));
typedef __bf16 bf16x8 __attribute__((ext_vector_type(8)));
typedef unsigned short u16;

__device__ __forceinline__ float bf2f(u16 u) {
    return __uint_as_float(((unsigned int)u) << 16);
}
__device__ __forceinline__ u16 f2bf(float f) {
    unsigned int u = __float_as_uint(f);
    u += 0x7fffu + ((u >> 16) & 1u);
    return (u16)(u >> 16);
}

// ---------------- zero init (stats | gacc contiguous) ----------------
__global__ void k_zero(float4* __restrict__ p, int n4) {
    int i = blockIdx.x * 256 + threadIdx.x;
    if (i < n4) p[i] = make_float4(0.f, 0.f, 0.f, 0.f);
}

// ---------------- pre-swizzle W1/W2 into MFMA B-fragment order (once per call) -----
__global__ __launch_bounds__(256) void k_prepw(const float* __restrict__ W1,
                                               const float* __restrict__ W2,
                                               bf16x8* __restrict__ wswz, int L) {
    int b = blockIdx.x >> 3;
    const float* W = (b < L) ? (W1 + (size_t)b * D * D)
                             : (W2 + (size_t)(b - L) * D * D);
    bf16x8* o = wswz + (size_t)b * 2048;
    int idx = ((blockIdx.x & 7) << 8) + threadIdx.x;   // 0..2047
    int lane_s = idx & 63;
    int f = idx >> 6;
    int n = ((f >> 2) << 4) | (lane_s & 15);
    int kb = ((f & 3) << 5) | ((lane_s >> 4) << 3);
    bf16x8 fr;
#pragma unroll
    for (int j = 0; j < 8; ++j) fr[j] = (__bf16)W[(kb + j) * D + n];
    o[idx] = fr;
}

// ============ bucketing: deterministic two-level, NO contended global atomics ======
__global__ __launch_bounds__(256) void k_hist(const int* __restrict__ dst,
                                              int* __restrict__ cnts, int E, int nb) {
    __shared__ int hist[1024];
    int tid = threadIdx.x;
    for (int i = tid; i < nb; i += 256) hist[i] = 0;
    __syncthreads();
    int e0 = blockIdx.x << 14;
    int e1 = e0 + 16384; if (e1 > E) e1 = E;
    for (int e = e0 + tid; e < e1; e += 256) atomicAdd(&hist[dst[e] >> 7], 1);
    __syncthreads();
    for (int i = tid; i < nb; i += 256) cnts[(blockIdx.x << 10) + i] = hist[i];
}

__global__ void k_off(int* __restrict__ cnts, int* __restrict__ btot, int nbk, int nb) {
    int b = blockIdx.x * 256 + threadIdx.x;
    if (b >= nb) return;
    int run = 0;
    for (int k = 0; k < nbk; ++k) {
        int idx = (k << 10) + b;
        int c = cnts[idx];
        cnts[idx] = run;
        run += c;
    }
    btot[b] = run;
}

__global__ __launch_bounds__(256) void k_scat(const int* __restrict__ src,
                                              const int* __restrict__ dst,
                                              const int* __restrict__ cnts,
                                              int* __restrict__ pairs, int E, int nb) {
    __shared__ int lbase[1024];
    __shared__ int lcur[1024];
    int tid = threadIdx.x;
    for (int i = tid; i < nb; i += 256) {
        lbase[i] = cnts[(blockIdx.x << 10) + i];
        lcur[i] = 0;
    }
    __syncthreads();
    int e0 = blockIdx.x << 14;
    int e1 = e0 + 16384; if (e1 > E) e1 = E;
    for (int e = e0 + tid; e < e1; e += 256) {
        int d = dst[e];
        int b = d >> 7;
        int pos = lbase[b] + atomicAdd(&lcur[b], 1);
        if (pos < 4096) pairs[(b << 12) + pos] = (src[e] << 7) | (d & 127);
    }
}

// ---------------- x fp32 -> bf16 (padded rows zeroed) ----------------
__global__ void k_cvt(const float* __restrict__ x, u16* __restrict__ o,
                      int M, int Mpad) {
    long e = ((long)blockIdx.x * 256 + threadIdx.x) * 4;
    if (e >= (long)Mpad * D) return;
    ushort4 r;
    if (e < (long)M * D) {
        float4 v = *(const float4*)(x + e);
        r.x = f2bf(v.x); r.y = f2bf(v.y); r.z = f2bf(v.z); r.w = f2bf(v.w);
    } else {
        r = make_ushort4(0, 0, 0, 0);
    }
    *(ushort4*)(o + e) = r;
}

// ---------------- bucket aggregation: local CSR in LDS, register accumulation -----
// grid split in halves (b0 offset) to shorten per-dispatch duration & expose GEMMs.
__global__ __launch_bounds__(512) void k_agg(
        const u16* __restrict__ h, const int* __restrict__ pairs,
        const int* __restrict__ bcnt, const float* __restrict__ eps, int layer,
        u16* __restrict__ out, int M, int Mpad, int b0) {
    __shared__ int lcnt[128];
    __shared__ int loff[128];
    __shared__ int lcur[128];
    __shared__ int ledge[4096];
    int tid = threadIdx.x;
    if (tid < 128) lcnt[tid] = 0;
    __syncthreads();

    int b = b0 + blockIdx.x;
    int cnt = bcnt[b];
    if (cnt > 4096) cnt = 4096;
    const int* pb = pairs + ((size_t)b << 12);

    for (int e = tid; e < cnt; e += 512)
        atomicAdd(&lcnt[pb[e] & 127], 1);
    __syncthreads();

    if (tid < 128) loff[tid] = lcnt[tid];
    __syncthreads();
    for (int off = 1; off < 128; off <<= 1) {
        int v = 0;
        if (tid < 128 && tid >= off) v = loff[tid - off];
        __syncthreads();
        if (tid < 128) loff[tid] += v;
        __syncthreads();
    }
    if (tid < 128) lcur[tid] = loff[tid] - lcnt[tid];
    __syncthreads();

    for (int e = tid; e < cnt; e += 512) {
        int p = pb[e];
        int pos = atomicAdd(&lcur[p & 127], 1);
        ledge[pos] = p >> 7;
    }
    __syncthreads();

    float e1 = 1.0f + eps[layer];
    int grp = tid >> 5;
    int c = (tid & 31) << 2;
    for (int pass = 0; pass < 8; ++pass) {
        int row = (pass << 4) + grp;
        int node = (b << 7) + row;
        if (node >= Mpad) continue;
        u16* op = out + ((size_t)node << 7) + c;
        if (node >= M) { *(ushort4*)op = make_ushort4(0, 0, 0, 0); continue; }
        ushort4 sv = *(const ushort4*)(h + ((size_t)node << 7) + c);
        float a0 = e1 * bf2f(sv.x), a1 = e1 * bf2f(sv.y);
        float a2 = e1 * bf2f(sv.z), a3 = e1 * bf2f(sv.w);
        int dd = lcnt[row];
        int s = loff[row] - dd;
        int i = 0;
        for (; i + 8 <= dd; i += 8) {
            int n0 = ledge[s + i],     n1 = ledge[s + i + 1];
            int n2 = ledge[s + i + 2], n3 = ledge[s + i + 3];
            int n4 = ledge[s + i + 4], n5 = ledge[s + i + 5];
            int n6 = ledge[s + i + 6], n7 = ledge[s + i + 7];
            ushort4 u0 = *(const ushort4*)(h + ((size_t)n0 << 7) + c);
            ushort4 u1 = *(const ushort4*)(h + ((size_t)n1 << 7) + c);
            ushort4 u2 = *(const ushort4*)(h + ((size_t)n2 << 7) + c);
            ushort4 u3 = *(const ushort4*)(h + ((size_t)n3 << 7) + c);
            ushort4 u4 = *(const ushort4*)(h + ((size_t)n4 << 7) + c);
            ushort4 u5 = *(const ushort4*)(h + ((size_t)n5 << 7) + c);
            ushort4 u6 = *(const ushort4*)(h + ((size_t)n6 << 7) + c);
            ushort4 u7 = *(const ushort4*)(h + ((size_t)n7 << 7) + c);
            a0 += bf2f(u0.x) + bf2f(u1.x) + bf2f(u2.x) + bf2f(u3.x)
                + bf2f(u4.x) + bf2f(u5.x) + bf2f(u6.x) + bf2f(u7.x);
            a1 += bf2f(u0.y) + bf2f(u1.y) + bf2f(u2.y) + bf2f(u3.y)
                + bf2f(u4.y) + bf2f(u5.y) + bf2f(u6.y) + bf2f(u7.y);
            a2 += bf2f(u0.z) + bf2f(u1.z) + bf2f(u2.z) + bf2f(u3.z)
                + bf2f(u4.z) + bf2f(u5.z) + bf2f(u6.z) + bf2f(u7.z);
            a3 += bf2f(u0.w) + bf2f(u1.w) + bf2f(u2.w) + bf2f(u3.w)
                + bf2f(u4.w) + bf2f(u5.w) + bf2f(u6.w) + bf2f(u7.w);
        }
        for (; i + 4 <= dd; i += 4) {
            int n0 = ledge[s + i],     n1 = ledge[s + i + 1];
            int n2 = ledge[s + i + 2], n3 = ledge[s + i + 3];
            ushort4 u0 = *(const ushort4*)(h + ((size_t)n0 << 7) + c);
            ushort4 u1 = *(const ushort4*)(h + ((size_t)n1 << 7) + c);
            ushort4 u2 = *(const ushort4*)(h + ((size_t)n2 << 7) + c);
            ushort4 u3 = *(const ushort4*)(h + ((size_t)n3 << 7) + c);
            a0 += bf2f(u0.x) + bf2f(u1.x) + bf2f(u2.x) + bf2f(u3.x);
            a1 += bf2f(u0.y) + bf2f(u1.y) + bf2f(u2.y) + bf2f(u3.y);
            a2 += bf2f(u0.z) + bf2f(u1.z) + bf2f(u2.z) + bf2f(u3.z);
            a3 += bf2f(u0.w) + bf2f(u1.w) + bf2f(u2.w) + bf2f(u3.w);
        }
        for (; i < dd; ++i) {
            int n0 = ledge[s + i];
            ushort4 u0 = *(const ushort4*)(h + ((size_t)n0 << 7) + c);
            a0 += bf2f(u0.x); a1 += bf2f(u0.y); a2 += bf2f(u0.z); a3 += bf2f(u0.w);
        }
        ushort4 r;
        r.x = f2bf(a0); r.y = f2bf(a1); r.z = f2bf(a2); r.w = f2bf(a3);
        *(ushort4*)op = r;
    }
}

// ---------------- GEMM1: A(bf16) @ W + b -> O(bf16) + BN stats (replicated) --------
// A-loads hoisted above W staging so their latency overlaps staging + barrier.
__global__ __launch_bounds__(256, 3) void k_gemm_bf(
        const u16* __restrict__ A, u16* __restrict__ O,
        const bf16x8* __restrict__ wz, const float* __restrict__ bias,
        float* __restrict__ stats, int M) {
    __shared__ union { bf16x8 w[2048]; u16 c[128 * CT_STRIDE]; } sh;
    __shared__ float blds[D], psum[4 * D], psq[4 * D];
    int tid = threadIdx.x;
    int wave = tid >> 6, lane = tid & 63;
    int m = lane & 15, quad = lane >> 4;
    int row0 = blockIdx.x * 128 + wave * 32;

    // prefetch all A fragments FIRST (latency hidden behind W staging)
    const u16* ap0 = A + (size_t)(row0 + m) * D + (quad << 3);
    const u16* ap1 = ap0 + (size_t)16 * D;
    bf16x8 a0[4], a1[4];
#pragma unroll
    for (int kc = 0; kc < 4; ++kc) {
        a0[kc] = *(const bf16x8*)(ap0 + (kc << 5));
        a1[kc] = *(const bf16x8*)(ap1 + (kc << 5));
    }

    for (int i = tid; i < 2048; i += 256) sh.w[i] = wz[i];
    if (tid < D) blds[tid] = bias[tid];
    __syncthreads();

    f32x4 z = {0.f, 0.f, 0.f, 0.f};
    f32x4 acc0[8], acc1[8];
#pragma unroll
    for (int t = 0; t < 8; ++t) { acc0[t] = z; acc1[t] = z; }

#pragma unroll
    for (int kc = 0; kc < 4; ++kc) {
#pragma unroll
        for (int t = 0; t < 8; ++t) {
            bf16x8 bf = sh.w[(((t << 2) | kc) << 6) | lane];
            acc0[t] = __builtin_amdgcn_mfma_f32_16x16x32_bf16(a0[kc], bf, acc0[t], 0, 0, 0);
            acc1[t] = __builtin_amdgcn_mfma_f32_16x16x32_bf16(a1[kc], bf, acc1[t], 0, 0, 0);
        }
    }
    __syncthreads();   // all waves done reading sh.w

    int lr0 = wave * 32 + (quad << 2);
    int gr0 = blockIdx.x * 128 + lr0;
#pragma unroll
    for (int t = 0; t < 8; ++t) {
        int cch = (t << 4) | m;
        float bc = blds[cch];
        float s = 0.f, q = 0.f;
#pragma unroll
        for (int r = 0; r < 4; ++r) {
            float v0 = acc0[t][r] + bc;
            sh.c[(lr0 + r) * CT_STRIDE + cch] = f2bf(v0);
            if (gr0 + r < M) { s += v0; q += v0 * v0; }
            float v1 = acc1[t][r] + bc;
            sh.c[(lr0 + 16 + r) * CT_STRIDE + cch] = f2bf(v1);
            if (gr0 + 16 + r < M) { s += v1; q += v1 * v1; }
        }
        s += __shfl_xor(s, 16); s += __shfl_xor(s, 32);
        q += __shfl_xor(q, 16); q += __shfl_xor(q, 32);
        if (quad == 0) { psum[wave * D + cch] = s; psq[wave * D + cch] = q; }
    }
    __syncthreads();

    int mrow = M - blockIdx.x * 128;
#pragma unroll
    for (int i = 0; i < 8; ++i) {
        int idx = (i << 8) + tid;
        int row = idx >> 4, ch8 = (idx & 15) << 3;
        if (row < mrow) {
            float4 v = *(const float4*)&sh.c[row * CT_STRIDE + ch8];
            *(float4*)(O + ((size_t)(blockIdx.x * 128 + row) << 7) + ch8) = v;
        }
    }
    if (tid < D) {
        float s = psum[tid] + psum[D + tid] + psum[2 * D + tid] + psum[3 * D + tid];
        float q = psq[tid] + psq[D + tid] + psq[2 * D + tid] + psq[3 * D + tid];
        float* st = stats + ((blockIdx.x & 7) << 8);
        atomicAdd(&st[tid], s);
        atomicAdd(&st[D + tid], q);
    }
}

// ---------------- GEMM2: BN1+ReLU on the fly -> @W + b, in-place, + stats2 ---------
__global__ __launch_bounds__(256, 3) void k_gemm_bn(
        u16* __restrict__ A, const bf16x8* __restrict__ wz,
        const float* __restrict__ bias, const float* __restrict__ stats_in,
        const float* __restrict__ gamma, const float* __restrict__ beta,
        float* __restrict__ stats_out, float invM, int M) {
    __shared__ union { bf16x8 w[2048]; u16 c[128 * CT_STRIDE]; } sh;
    __shared__ float blds[D], s_sc[D], s_sh[D], psum[4 * D], psq[4 * D];
    int tid = threadIdx.x;
    int wave = tid >> 6, lane = tid & 63;
    int m = lane & 15, quad = lane >> 4;
    int row0 = blockIdx.x * 128 + wave * 32;

    // prefetch raw A fragments FIRST
    const u16* ap0 = A + (size_t)(row0 + m) * D + (quad << 3);
    const u16* ap1 = ap0 + (size_t)16 * D;
    ushort4 p[4][2], qv[4][2];
#pragma unroll
    for (int kc = 0; kc < 4; ++kc) {
        p[kc][0]  = *(const ushort4*)(ap0 + (kc << 5));
        p[kc][1]  = *(const ushort4*)(ap0 + (kc << 5) + 4);
        qv[kc][0] = *(const ushort4*)(ap1 + (kc << 5));
        qv[kc][1] = *(const ushort4*)(ap1 + (kc << 5) + 4);
    }

    for (int i = tid; i < 2048; i += 256) sh.w[i] = wz[i];
    if (tid < D) {
        float s = 0.f, q = 0.f;
#pragma unroll
        for (int r = 0; r < 8; ++r) {
            s += stats_in[(r << 8) + tid];
            q += stats_in[(r << 8) + D + tid];
        }
        float mean = s * invM;
        float var = q * invM - mean * mean;
        float sc = rsqrtf(var + 1e-5f) * gamma[tid];
        s_sc[tid] = sc;
        s_sh[tid] = beta[tid] - mean * sc;
        blds[tid] = bias[tid];
    }
    __syncthreads();

    f32x4 z = {0.f, 0.f, 0.f, 0.f};
    f32x4 acc0[8], acc1[8];
#pragma unroll
    for (int t = 0; t < 8; ++t) { acc0[t] = z; acc1[t] = z; }

#pragma unroll
    for (int kc = 0; kc < 4; ++kc) {
        int kb = (kc << 5) | (quad << 3);
        float4 c0 = *(const float4*)&s_sc[kb];
        float4 c1 = *(const float4*)&s_sc[kb + 4];
        float4 h0 = *(const float4*)&s_sh[kb];
        float4 h1 = *(const float4*)&s_sh[kb + 4];
        ushort4 p0 = p[kc][0], p1 = p[kc][1];
        ushort4 q0 = qv[kc][0], q1 = qv[kc][1];
        bf16x8 af0, af1;
        af0[0] = (__bf16)fmaxf(0.f, fmaf(bf2f(p0.x), c0.x, h0.x));
        af0[1] = (__bf16)fmaxf(0.f, fmaf(bf2f(p0.y), c0.y, h0.y));
        af0[2] = (__bf16)fmaxf(0.f, fmaf(bf2f(p0.z), c0.z, h0.z));
        af0[3] = (__bf16)fmaxf(0.f, fmaf(bf2f(p0.w), c0.w, h0.w));
        af0[4] = (__bf16)fmaxf(0.f, fmaf(bf2f(p1.x), c1.x, h1.x));
        af0[5] = (__bf16)fmaxf(0.f, fmaf(bf2f(p1.y), c1.y, h1.y));
        af0[6] = (__bf16)fmaxf(0.f, fmaf(bf2f(p1.z), c1.z, h1.z));
        af0[7] = (__bf16)fmaxf(0.f, fmaf(bf2f(p1.w), c1.w, h1.w));
        af1[0] = (__bf16)fmaxf(0.f, fmaf(bf2f(q0.x), c0.x, h0.x));
        af1[1] = (__bf16)fmaxf(0.f, fmaf(bf2f(q0.y), c0.y, h0.y));
        af1[2] = (__bf16)fmaxf(0.f, fmaf(bf2f(q0.z), c0.z, h0.z));
        af1[3] = (__bf16)fmaxf(0.f, fmaf(bf2f(q0.w), c0.w, h0.w));
        af1[4] = (__bf16)fmaxf(0.f, fmaf(bf2f(q1.x), c1.x, h1.x));
        af1[5] = (__bf16)fmaxf(0.f, fmaf(bf2f(q1.y), c1.y, h1.y));
        af1[6] = (__bf16)fmaxf(0.f, fmaf(bf2f(q1.z), c1.z, h1.z));
        af1[7] = (__bf16)fmaxf(0.f, fmaf(bf2f(q1.w), c1.w, h1.w));
#pragma unroll
        for (int t = 0; t < 8; ++t) {
            bf16x8 bf = sh.w[(((t << 2) | kc) << 6) | lane];
            acc0[t] = __builtin_amdgcn_mfma_f32_16x16x32_bf16(af0, bf, acc0[t], 0, 0, 0);
            acc1[t] = __builtin_amdgcn_mfma_f32_16x16x32_bf16(af1, bf, acc1[t], 0, 0, 0);
        }
    }
    __syncthreads();

    int lr0 = wave * 32 + (quad << 2);
    int gr0 = blockIdx.x * 128 + lr0;
#pragma unroll
    for (int t = 0; t < 8; ++t) {
        int cch = (t << 4) | m;
        float bc = blds[cch];
        float s = 0.f, q = 0.f;
#pragma unroll
        for (int r = 0; r < 4; ++r) {
            float v0 = acc0[t][r] + bc;
            sh.c[(lr0 + r) * CT_STRIDE + cch] = f2bf(v0);
            if (gr0 + r < M) { s += v0; q += v0 * v0; }
            float v1 = acc1[t][r] + bc;
            sh.c[(lr0 + 16 + r) * CT_STRIDE + cch] = f2bf(v1);
            if (gr0 + 16 + r < M) { s += v1; q += v1 * v1; }
        }
        s += __shfl_xor(s, 16); s += __shfl_xor(s, 32);
        q += __shfl_xor(q, 16); q += __shfl_xor(q, 32);
        if (quad == 0) { psum[wave * D + cch] = s; psq[wave * D + cch] = q; }
    }
    __syncthreads();

    int mrow = M - blockIdx.x * 128;
#pragma unroll
    for (int i = 0; i < 8; ++i) {
        int idx = (i << 8) + tid;
        int row = idx >> 4, ch8 = (idx & 15) << 3;
        if (row < mrow) {
            float4 v = *(const float4*)&sh.c[row * CT_STRIDE + ch8];
            *(float4*)(A + ((size_t)(blockIdx.x * 128 + row) << 7) + ch8) = v;
        }
    }
    if (tid < D) {
        float s = psum[tid] + psum[D + tid] + psum[2 * D + tid] + psum[3 * D + tid];
        float q = psq[tid] + psq[D + tid] + psq[2 * D + tid] + psq[3 * D + tid];
        float* st = stats_out + ((blockIdx.x & 7) << 8);
        atomicAdd(&st[tid], s);
        atomicAdd(&st[D + tid], q);
    }
}

// ---------------- BN2 + ReLU -> bf16 h, + fused weighted graph pooling -------------
__global__ __launch_bounds__(256) void k_bn2pool(
        const u16* __restrict__ y, const float* __restrict__ stats,
        const float* __restrict__ gamma, const float* __restrict__ beta,
        const int* __restrict__ gids, const float* __restrict__ fw,
        int layer, u16* __restrict__ hout, float* __restrict__ gacc,
        float invM, int M) {
    int t = threadIdx.x;
    int c = (t & 31) << 2;
    int strip = t >> 5;
    long base = (long)blockIdx.x * 64 + (long)strip * 8;
    if (base >= M) return;
    long nend = base + 8; if (nend > M) nend = M;
    float sc[4], shv[4];
#pragma unroll
    for (int j = 0; j < 4; ++j) {
        float s = 0.f, q = 0.f;
#pragma unroll
        for (int r = 0; r < 8; ++r) {
            s += stats[(r << 8) + c + j];
            q += stats[(r << 8) + D + c + j];
        }
        float mean = s * invM;
        float sv = rsqrtf(q * invM - mean * mean + 1e-5f) * gamma[c + j];
        sc[j] = sv;
        shv[j] = beta[c + j] - mean * sv;
    }
    float wl = fw[layer];
    int cur = -1;
    float a0 = 0.f, a1 = 0.f, a2 = 0.f, a3 = 0.f;
    for (long node = base; node < nend; ++node) {
        ushort4 v = *(const ushort4*)(y + (node << 7) + c);
        float h0 = fmaxf(0.f, fmaf(bf2f(v.x), sc[0], shv[0]));
        float h1 = fmaxf(0.f, fmaf(bf2f(v.y), sc[1], shv[1]));
        float h2 = fmaxf(0.f, fmaf(bf2f(v.z), sc[2], shv[2]));
        float h3 = fmaxf(0.f, fmaf(bf2f(v.w), sc[3], shv[3]));
        ushort4 r;
        r.x = f2bf(h0); r.y = f2bf(h1); r.z = f2bf(h2); r.w = f2bf(h3);
        *(ushort4*)(hout + (node << 7) + c) = r;
        int gid = gids[node];
        if (gid != cur) {
            if (cur >= 0) {
                float* gp = gacc + ((size_t)cur << 7) + c;
                atomicAdd(gp, wl * a0); atomicAdd(gp + 1, wl * a1);
                atomicAdd(gp + 2, wl * a2); atomicAdd(gp + 3, wl * a3);
            }
            cur = gid;
            a0 = a1 = a2 = a3 = 0.f;
        }
        a0 += h0; a1 += h1; a2 += h2; a3 += h3;
    }
    if (cur >= 0) {
        float* gp = gacc + ((size_t)cur << 7) + c;
        atomicAdd(gp, wl * a0); atomicAdd(gp + 1, wl * a1);
        atomicAdd(gp + 2, wl * a2); atomicAdd(gp + 3, wl * a3);
    }
}

// ---------------- final: out = gacc(Gx128) @ Wp(128x10) + bp ----------------
__global__ void k_final(const float* __restrict__ gacc, const float* __restrict__ Wp,
                        const float* __restrict__ bp, float* __restrict__ out) {
    __shared__ float w[D * DOUT];
    __shared__ float bb[DOUT];
    int t = threadIdx.x;
    for (int i = t; i < D * DOUT; i += blockDim.x) w[i] = Wp[i];
    if (t < DOUT) bb[t] = bp[t];
    __syncthreads();
    float acc[DOUT];
#pragma unroll
    for (int o = 0; o < DOUT; ++o) acc[o] = bb[o];
    for (int k = 0; k < D; ++k) {
        float a = gacc[(size_t)t * D + k];
#pragma unroll
        for (int o = 0; o < DOUT; ++o) acc[o] += a * w[k * DOUT + o];
    }
#pragma unroll
    for (int o = 0; o < DOUT; ++o) out[(size_t)t * DOUT + o] = acc[o];
}

extern "C" void kernel_launch(void* const* d_in, const int* in_sizes, int n_in,
                              void* d_out, int out_size, void* d_ws, size_t ws_size,
                              hipStream_t stream) {
    const float* x    = (const float*)d_in[0];
    const int* esrc   = (const int*)d_in[1];
    const int* edst   = (const int*)d_in[2];
    const int* gids   = (const int*)d_in[3];
    const float* eps  = (const float*)d_in[4];
    const float* fw   = (const float*)d_in[5];
    const float* W1   = (const float*)d_in[6];
    const float* b1   = (const float*)d_in[7];
    const float* g1   = (const float*)d_in[8];
    const float* bt1  = (const float*)d_in[9];
    const float* W2   = (const float*)d_in[10];
    const float* b2   = (const float*)d_in[11];
    const float* g2   = (const float*)d_in[12];
    const float* bt2  = (const float*)d_in[13];
    const float* Wp   = (const float*)d_in[14];
    const float* bp   = (const float*)d_in[15];
    float* out        = (float*)d_out;

    const int M = in_sizes[3];     // 100000 nodes
    const int E = in_sizes[1];     // 1600000 edges
    const int L = in_sizes[4];     // 4 layers
    const int G = out_size / DOUT; // 256 graphs
    const int nb  = (M + 127) >> 7;           // buckets of 128 dst nodes (782)
    const int Mpad = nb << 7;
    const int nbk = (E + 16383) >> 14;        // 16K-edge chunks (98)
    const int nbh = nb >> 1;                  // half grid for agg split
    const float invM = 1.0f / (float)M;

    char* ws = (char*)d_ws;
    u16* bufP  = (u16*)ws;  ws += (size_t)Mpad * D * 2;   // pooled bf16
    u16* bufT  = (u16*)ws;  ws += (size_t)Mpad * D * 2;   // MLP temp bf16
    u16* bufH  = (u16*)ws;  ws += (size_t)Mpad * D * 2;   // hidden bf16
    int* pairs = (int*)ws;  ws += (size_t)nb * 4096 * 4;  // packed (src<<7)|(dst&127)
    int* cnts  = (int*)ws;  ws += (size_t)nbk * 1024 * 4; // per-(chunk,bucket) bases
    int* btot  = (int*)ws;  ws += 1024 * 4;               // bucket totals
    bf16x8* wswz = (bf16x8*)ws; ws += (size_t)2 * L * 2048 * 16;  // swizzled W
    // contiguous zero region: stats (8 replicas) | gacc
    float* stats = (float*)ws; ws += (size_t)L * 4096 * 4;
    float* gacc  = (float*)ws; ws += (size_t)G * D * 4;

    int zbytes = L * 4096 * 4 + G * D * 4;
    int n4 = zbytes / 16;
    k_zero<<<(n4 + 255) / 256, 256, 0, stream>>>((float4*)stats, n4);

    k_prepw<<<2 * L * 8, 256, 0, stream>>>(W1, W2, wswz, L);
    k_hist<<<nbk, 256, 0, stream>>>(edst, cnts, E, nb);
    k_off<<<(nb + 255) / 256, 256, 0, stream>>>(cnts, btot, nbk, nb);
    k_scat<<<nbk, 256, 0, stream>>>(esrc, edst, cnts, pairs, E, nb);
    k_cvt<<<(Mpad * (D / 4) + 255) / 256, 256, 0, stream>>>(x, bufH, M, Mpad);

    int gemm_grid = Mpad / 128;
    int pool_grid = (M + 63) / 64;
    for (int l = 0; l < L; ++l) {
        float* st1 = stats + (size_t)l * 4096;
        float* st2 = st1 + 2048;
        k_agg<<<nbh, 512, 0, stream>>>(bufH, pairs, btot, eps, l, bufP, M, Mpad, 0);
        k_agg<<<nb - nbh, 512, 0, stream>>>(bufH, pairs, btot, eps, l, bufP, M, Mpad, nbh);
        k_gemm_bf<<<gemm_grid, 256, 0, stream>>>(bufP, bufT, wswz + (size_t)l * 2048,
                                                 b1 + (size_t)l * D, st1, M);
        k_gemm_bn<<<gemm_grid, 256, 0, stream>>>(bufT, wswz + (size_t)(L + l) * 2048,
                                                 b2 + (size_t)l * D, st1,
                                                 g1 + (size_t)l * D, bt1 + (size_t)l * D,
                                                 st2, invM, M);
        k_bn2pool<<<pool_grid, 256, 0, stream>>>(bufT, st2, g2 + (size_t)l * D,
                                                 bt2 + (size_t)l * D, gids, fw, l,
                                                 bufH, gacc, invM, M);
    }
    k_final<<<1, G, 0, stream>>>(gacc, Wp, bp, out);
}

// Round 9
// 775.425 us; speedup vs baseline: 1.0554x; 1.0554x over previous
//
#include <hip/hip_runtime.h>

#define D 128            // hidden dim
#define DOUT 10
#define CT_STRIDE 152    // C-tile LDS row stride in u16

typedef float f32x4 __attribute__((ext_vector_type(4)));
typedef __bf16 bf16x8 __attribute__((ext_vector_type(8)));
typedef unsigned short u16;

__device__ __forceinline__ float bf2f(u16 u) {
    return __uint_as_float(((unsigned int)u) << 16);
}
__device__ __forceinline__ u16 f2bf(float f) {
    unsigned int u = __float_as_uint(f);
    u += 0x7fffu + ((u >> 16) & 1u);
    return (u16)(u >> 16);
}

// ---------------- zero init (stats | gacc contiguous) ----------------
__global__ void k_zero(float4* __restrict__ p, int n4) {
    int i = blockIdx.x * 256 + threadIdx.x;
    if (i < n4) p[i] = make_float4(0.f, 0.f, 0.f, 0.f);
}

// ---------------- pre-swizzle W1/W2 into MFMA B-fragment order (once per call) -----
__global__ __launch_bounds__(256) void k_prepw(const float* __restrict__ W1,
                                               const float* __restrict__ W2,
                                               bf16x8* __restrict__ wswz, int L) {
    int b = blockIdx.x >> 3;
    const float* W = (b < L) ? (W1 + (size_t)b * D * D)
                             : (W2 + (size_t)(b - L) * D * D);
    bf16x8* o = wswz + (size_t)b * 2048;
    int idx = ((blockIdx.x & 7) << 8) + threadIdx.x;   // 0..2047
    int lane_s = idx & 63;
    int f = idx >> 6;
    int n = ((f >> 2) << 4) | (lane_s & 15);
    int kb = ((f & 3) << 5) | ((lane_s >> 4) << 3);
    bf16x8 fr;
#pragma unroll
    for (int j = 0; j < 8; ++j) fr[j] = (__bf16)W[(kb + j) * D + n];
    o[idx] = fr;
}

// ============ bucketing: 2048-edge chunks (round-8 lesson: 98 blocks starved the
// chip and serialized LDS atomic-returns; 782 blocks / 8-per-thread hides it) ======
__global__ __launch_bounds__(256) void k_hist(const int* __restrict__ dst,
                                              int* __restrict__ cnts, int E, int nb) {
    __shared__ int hist[1024];
    int tid = threadIdx.x;
    for (int i = tid; i < nb; i += 256) hist[i] = 0;
    __syncthreads();
    int e0 = blockIdx.x << 11;
    int e1 = e0 + 2048; if (e1 > E) e1 = E;
    for (int e = e0 + tid; e < e1; e += 256) atomicAdd(&hist[dst[e] >> 7], 1);
    __syncthreads();
    for (int i = tid; i < nb; i += 256) cnts[(blockIdx.x << 10) + i] = hist[i];
}

// per-bucket exclusive scan across chunk-blocks; one WAVE per bucket, shuffle scan.
__global__ __launch_bounds__(256) void k_off(int* __restrict__ cnts,
                                             int* __restrict__ btot,
                                             int nbk, int nb) {
    int wave = threadIdx.x >> 6, lane = threadIdx.x & 63;
    int b = blockIdx.x * 4 + wave;
    if (b >= nb) return;
    int carry = 0;
    for (int base = 0; base < nbk; base += 64) {
        int idx = base + lane;
        int orig = (idx < nbk) ? cnts[(idx << 10) + b] : 0;
        int c = orig;
#pragma unroll
        for (int off = 1; off < 64; off <<= 1) {
            int v = __shfl_up(c, off);
            if (lane >= off) c += v;
        }
        if (idx < nbk) cnts[(idx << 10) + b] = carry + (c - orig);  // exclusive
        carry += __shfl(c, 63);
    }
    if (lane == 0) btot[b] = carry;
}

__global__ __launch_bounds__(256) void k_scat(const int* __restrict__ src,
                                              const int* __restrict__ dst,
                                              const int* __restrict__ cnts,
                                              int* __restrict__ pairs, int E, int nb) {
    __shared__ int lbase[1024];
    __shared__ int lcur[1024];
    int tid = threadIdx.x;
    for (int i = tid; i < nb; i += 256) {
        lbase[i] = cnts[(blockIdx.x << 10) + i];
        lcur[i] = 0;
    }
    __syncthreads();
    int e0 = blockIdx.x << 11;
    int e1 = e0 + 2048; if (e1 > E) e1 = E;
    for (int e = e0 + tid; e < e1; e += 256) {
        int d = dst[e];
        int b = d >> 7;
        int pos = lbase[b] + atomicAdd(&lcur[b], 1);
        if (pos < 4096) pairs[(b << 12) + pos] = (src[e] << 7) | (d & 127);
    }
}

// ---------------- x fp32 -> bf16 (padded rows zeroed) ----------------
__global__ void k_cvt(const float* __restrict__ x, u16* __restrict__ o,
                      int M, int Mpad) {
    long e = ((long)blockIdx.x * 256 + threadIdx.x) * 4;
    if (e >= (long)Mpad * D) return;
    ushort4 r;
    if (e < (long)M * D) {
        float4 v = *(const float4*)(x + e);
        r.x = f2bf(v.x); r.y = f2bf(v.y); r.z = f2bf(v.z); r.w = f2bf(v.w);
    } else {
        r = make_ushort4(0, 0, 0, 0);
    }
    *(ushort4*)(o + e) = r;
}

// ---------------- bucket aggregation: local CSR in LDS, register accumulation -----
__global__ __launch_bounds__(512) void k_agg(
        const u16* __restrict__ h, const int* __restrict__ pairs,
        const int* __restrict__ bcnt, const float* __restrict__ eps, int layer,
        u16* __restrict__ out, int M, int Mpad, int b0) {
    __shared__ int lcnt[128];
    __shared__ int loff[128];
    __shared__ int lcur[128];
    __shared__ int ledge[4096];
    int tid = threadIdx.x;
    if (tid < 128) lcnt[tid] = 0;
    __syncthreads();

    int b = b0 + blockIdx.x;
    int cnt = bcnt[b];
    if (cnt > 4096) cnt = 4096;
    const int* pb = pairs + ((size_t)b << 12);

    for (int e = tid; e < cnt; e += 512)
        atomicAdd(&lcnt[pb[e] & 127], 1);
    __syncthreads();

    if (tid < 128) loff[tid] = lcnt[tid];
    __syncthreads();
    for (int off = 1; off < 128; off <<= 1) {
        int v = 0;
        if (tid < 128 && tid >= off) v = loff[tid - off];
        __syncthreads();
        if (tid < 128) loff[tid] += v;
        __syncthreads();
    }
    if (tid < 128) lcur[tid] = loff[tid] - lcnt[tid];
    __syncthreads();

    for (int e = tid; e < cnt; e += 512) {
        int p = pb[e];
        int pos = atomicAdd(&lcur[p & 127], 1);
        ledge[pos] = p >> 7;
    }
    __syncthreads();

    float e1 = 1.0f + eps[layer];
    int grp = tid >> 5;
    int c = (tid & 31) << 2;
    for (int pass = 0; pass < 8; ++pass) {
        int row = (pass << 4) + grp;
        int node = (b << 7) + row;
        if (node >= Mpad) continue;
        u16* op = out + ((size_t)node << 7) + c;
        if (node >= M) { *(ushort4*)op = make_ushort4(0, 0, 0, 0); continue; }
        ushort4 sv = *(const ushort4*)(h + ((size_t)node << 7) + c);
        float a0 = e1 * bf2f(sv.x), a1 = e1 * bf2f(sv.y);
        float a2 = e1 * bf2f(sv.z), a3 = e1 * bf2f(sv.w);
        int dd = lcnt[row];
        int s = loff[row] - dd;
        int i = 0;
        for (; i + 8 <= dd; i += 8) {
            int n0 = ledge[s + i],     n1 = ledge[s + i + 1];
            int n2 = ledge[s + i + 2], n3 = ledge[s + i + 3];
            int n4 = ledge[s + i + 4], n5 = ledge[s + i + 5];
            int n6 = ledge[s + i + 6], n7 = ledge[s + i + 7];
            ushort4 u0 = *(const ushort4*)(h + ((size_t)n0 << 7) + c);
            ushort4 u1 = *(const ushort4*)(h + ((size_t)n1 << 7) + c);
            ushort4 u2 = *(const ushort4*)(h + ((size_t)n2 << 7) + c);
            ushort4 u3 = *(const ushort4*)(h + ((size_t)n3 << 7) + c);
            ushort4 u4 = *(const ushort4*)(h + ((size_t)n4 << 7) + c);
            ushort4 u5 = *(const ushort4*)(h + ((size_t)n5 << 7) + c);
            ushort4 u6 = *(const ushort4*)(h + ((size_t)n6 << 7) + c);
            ushort4 u7 = *(const ushort4*)(h + ((size_t)n7 << 7) + c);
            a0 += bf2f(u0.x) + bf2f(u1.x) + bf2f(u2.x) + bf2f(u3.x)
                + bf2f(u4.x) + bf2f(u5.x) + bf2f(u6.x) + bf2f(u7.x);
            a1 += bf2f(u0.y) + bf2f(u1.y) + bf2f(u2.y) + bf2f(u3.y)
                + bf2f(u4.y) + bf2f(u5.y) + bf2f(u6.y) + bf2f(u7.y);
            a2 += bf2f(u0.z) + bf2f(u1.z) + bf2f(u2.z) + bf2f(u3.z)
                + bf2f(u4.z) + bf2f(u5.z) + bf2f(u6.z) + bf2f(u7.z);
            a3 += bf2f(u0.w) + bf2f(u1.w) + bf2f(u2.w) + bf2f(u3.w)
                + bf2f(u4.w) + bf2f(u5.w) + bf2f(u6.w) + bf2f(u7.w);
        }
        for (; i + 4 <= dd; i += 4) {
            int n0 = ledge[s + i],     n1 = ledge[s + i + 1];
            int n2 = ledge[s + i + 2], n3 = ledge[s + i + 3];
            ushort4 u0 = *(const ushort4*)(h + ((size_t)n0 << 7) + c);
            ushort4 u1 = *(const ushort4*)(h + ((size_t)n1 << 7) + c);
            ushort4 u2 = *(const ushort4*)(h + ((size_t)n2 << 7) + c);
            ushort4 u3 = *(const ushort4*)(h + ((size_t)n3 << 7) + c);
            a0 += bf2f(u0.x) + bf2f(u1.x) + bf2f(u2.x) + bf2f(u3.x);
            a1 += bf2f(u0.y) + bf2f(u1.y) + bf2f(u2.y) + bf2f(u3.y);
            a2 += bf2f(u0.z) + bf2f(u1.z) + bf2f(u2.z) + bf2f(u3.z);
            a3 += bf2f(u0.w) + bf2f(u1.w) + bf2f(u2.w) + bf2f(u3.w);
        }
        for (; i < dd; ++i) {
            int n0 = ledge[s + i];
            ushort4 u0 = *(const ushort4*)(h + ((size_t)n0 << 7) + c);
            a0 += bf2f(u0.x); a1 += bf2f(u0.y); a2 += bf2f(u0.z); a3 += bf2f(u0.w);
        }
        ushort4 r;
        r.x = f2bf(a0); r.y = f2bf(a1); r.z = f2bf(a2); r.w = f2bf(a3);
        *(ushort4*)op = r;
    }
}

// ---------------- GEMM1: 64-row tile, 4 blocks/CU; A-prefetch above W staging ------
__global__ __launch_bounds__(256, 4) void k_gemm_bf(
        const u16* __restrict__ A, u16* __restrict__ O,
        const bf16x8* __restrict__ wz, const float* __restrict__ bias,
        float* __restrict__ stats, int M) {
    __shared__ union { bf16x8 w[2048]; u16 c[64 * CT_STRIDE]; } sh;  // 32 KB
    __shared__ float blds[D], psum[4 * D], psq[4 * D];
    int tid = threadIdx.x;
    int wave = tid >> 6, lane = tid & 63;
    int m = lane & 15, quad = lane >> 4;
    int row0 = blockIdx.x * 64 + wave * 16;

    const u16* ap = A + (size_t)(row0 + m) * D + (quad << 3);
    bf16x8 a[4];
#pragma unroll
    for (int kc = 0; kc < 4; ++kc) a[kc] = *(const bf16x8*)(ap + (kc << 5));

    for (int i = tid; i < 2048; i += 256) sh.w[i] = wz[i];
    if (tid < D) blds[tid] = bias[tid];
    __syncthreads();

    f32x4 z = {0.f, 0.f, 0.f, 0.f};
    f32x4 acc[8];
#pragma unroll
    for (int t = 0; t < 8; ++t) acc[t] = z;

#pragma unroll
    for (int kc = 0; kc < 4; ++kc)
#pragma unroll
        for (int t = 0; t < 8; ++t)
            acc[t] = __builtin_amdgcn_mfma_f32_16x16x32_bf16(
                a[kc], sh.w[(((t << 2) | kc) << 6) | lane], acc[t], 0, 0, 0);
    __syncthreads();   // done reading sh.w

    int lr0 = wave * 16 + (quad << 2);
    int gr0 = blockIdx.x * 64 + lr0;
#pragma unroll
    for (int t = 0; t < 8; ++t) {
        int cch = (t << 4) | m;
        float bc = blds[cch];
        float s = 0.f, q = 0.f;
#pragma unroll
        for (int r = 0; r < 4; ++r) {
            float v = acc[t][r] + bc;
            sh.c[(lr0 + r) * CT_STRIDE + cch] = f2bf(v);
            if (gr0 + r < M) { s += v; q += v * v; }
        }
        s += __shfl_xor(s, 16); s += __shfl_xor(s, 32);
        q += __shfl_xor(q, 16); q += __shfl_xor(q, 32);
        if (quad == 0) { psum[wave * D + cch] = s; psq[wave * D + cch] = q; }
    }
    __syncthreads();

    int mrow = M - blockIdx.x * 64;
#pragma unroll
    for (int i = 0; i < 4; ++i) {
        int idx = (i << 8) + tid;
        int row = idx >> 4, ch8 = (idx & 15) << 3;
        if (row < mrow) {
            float4 v = *(const float4*)&sh.c[row * CT_STRIDE + ch8];
            *(float4*)(O + ((size_t)(blockIdx.x * 64 + row) << 7) + ch8) = v;
        }
    }
    if (tid < D) {
        float s = psum[tid] + psum[D + tid] + psum[2 * D + tid] + psum[3 * D + tid];
        float q = psq[tid] + psq[D + tid] + psq[2 * D + tid] + psq[3 * D + tid];
        float* st = stats + ((blockIdx.x & 7) << 8);
        atomicAdd(&st[tid], s);
        atomicAdd(&st[D + tid], q);
    }
}

// ---------------- GEMM2: BN1+ReLU on the fly -> @W + b, in-place, + stats2 ---------
__global__ __launch_bounds__(256, 4) void k_gemm_bn(
        u16* __restrict__ A, const bf16x8* __restrict__ wz,
        const float* __restrict__ bias, const float* __restrict__ stats_in,
        const float* __restrict__ gamma, const float* __restrict__ beta,
        float* __restrict__ stats_out, float invM, int M) {
    __shared__ union { bf16x8 w[2048]; u16 c[64 * CT_STRIDE]; } sh;
    __shared__ float blds[D], s_sc[D], s_sh[D], psum[4 * D], psq[4 * D];
    int tid = threadIdx.x;
    int wave = tid >> 6, lane = tid & 63;
    int m = lane & 15, quad = lane >> 4;
    int row0 = blockIdx.x * 64 + wave * 16;

    const u16* ap = A + (size_t)(row0 + m) * D + (quad << 3);
    ushort4 p[4][2];
#pragma unroll
    for (int kc = 0; kc < 4; ++kc) {
        p[kc][0] = *(const ushort4*)(ap + (kc << 5));
        p[kc][1] = *(const ushort4*)(ap + (kc << 5) + 4);
    }

    for (int i = tid; i < 2048; i += 256) sh.w[i] = wz[i];
    if (tid < D) {
        float s = 0.f, q = 0.f;
#pragma unroll
        for (int r = 0; r < 8; ++r) {
            s += stats_in[(r << 8) + tid];
            q += stats_in[(r << 8) + D + tid];
        }
        float mean = s * invM;
        float var = q * invM - mean * mean;
        float sc = rsqrtf(var + 1e-5f) * gamma[tid];
        s_sc[tid] = sc;
        s_sh[tid] = beta[tid] - mean * sc;
        blds[tid] = bias[tid];
    }
    __syncthreads();

    f32x4 z = {0.f, 0.f, 0.f, 0.f};
    f32x4 acc[8];
#pragma unroll
    for (int t = 0; t < 8; ++t) acc[t] = z;

#pragma unroll
    for (int kc = 0; kc < 4; ++kc) {
        int kb = (kc << 5) | (quad << 3);
        float4 c0 = *(const float4*)&s_sc[kb];
        float4 c1 = *(const float4*)&s_sc[kb + 4];
        float4 h0 = *(const float4*)&s_sh[kb];
        float4 h1 = *(const float4*)&s_sh[kb + 4];
        ushort4 p0 = p[kc][0], p1 = p[kc][1];
        bf16x8 af;
        af[0] = (__bf16)fmaxf(0.f, fmaf(bf2f(p0.x), c0.x, h0.x));
        af[1] = (__bf16)fmaxf(0.f, fmaf(bf2f(p0.y), c0.y, h0.y));
        af[2] = (__bf16)fmaxf(0.f, fmaf(bf2f(p0.z), c0.z, h0.z));
        af[3] = (__bf16)fmaxf(0.f, fmaf(bf2f(p0.w), c0.w, h0.w));
        af[4] = (__bf16)fmaxf(0.f, fmaf(bf2f(p1.x), c1.x, h1.x));
        af[5] = (__bf16)fmaxf(0.f, fmaf(bf2f(p1.y), c1.y, h1.y));
        af[6] = (__bf16)fmaxf(0.f, fmaf(bf2f(p1.z), c1.z, h1.z));
        af[7] = (__bf16)fmaxf(0.f, fmaf(bf2f(p1.w), c1.w, h1.w));
#pragma unroll
        for (int t = 0; t < 8; ++t)
            acc[t] = __builtin_amdgcn_mfma_f32_16x16x32_bf16(
                af, sh.w[(((t << 2) | kc) << 6) | lane], acc[t], 0, 0, 0);
    }
    __syncthreads();

    int lr0 = wave * 16 + (quad << 2);
    int gr0 = blockIdx.x * 64 + lr0;
#pragma unroll
    for (int t = 0; t < 8; ++t) {
        int cch = (t << 4) | m;
        float bc = blds[cch];
        float s = 0.f, q = 0.f;
#pragma unroll
        for (int r = 0; r < 4; ++r) {
            float v = acc[t][r] + bc;
            sh.c[(lr0 + r) * CT_STRIDE + cch] = f2bf(v);
            if (gr0 + r < M) { s += v; q += v * v; }
        }
        s += __shfl_xor(s, 16); s += __shfl_xor(s, 32);
        q += __shfl_xor(q, 16); q += __shfl_xor(q, 32);
        if (quad == 0) { psum[wave * D + cch] = s; psq[wave * D + cch] = q; }
    }
    __syncthreads();

    int mrow = M - blockIdx.x * 64;
#pragma unroll
    for (int i = 0; i < 4; ++i) {
        int idx = (i << 8) + tid;
        int row = idx >> 4, ch8 = (idx & 15) << 3;
        if (row < mrow) {
            float4 v = *(const float4*)&sh.c[row * CT_STRIDE + ch8];
            *(float4*)(A + ((size_t)(blockIdx.x * 64 + row) << 7) + ch8) = v;
        }
    }
    if (tid < D) {
        float s = psum[tid] + psum[D + tid] + psum[2 * D + tid] + psum[3 * D + tid];
        float q = psq[tid] + psq[D + tid] + psq[2 * D + tid] + psq[3 * D + tid];
        float* st = stats_out + ((blockIdx.x & 7) << 8);
        atomicAdd(&st[tid], s);
        atomicAdd(&st[D + tid], q);
    }
}

// ---------------- BN2 + ReLU -> bf16 h, + fused weighted graph pooling -------------
__global__ __launch_bounds__(256) void k_bn2pool(
        const u16* __restrict__ y, const float* __restrict__ stats,
        const float* __restrict__ gamma, const float* __restrict__ beta,
        const int* __restrict__ gids, const float* __restrict__ fw,
        int layer, u16* __restrict__ hout, float* __restrict__ gacc,
        float invM, int M) {
    int t = threadIdx.x;
    int c = (t & 31) << 2;
    int strip = t >> 5;
    long base = (long)blockIdx.x * 64 + (long)strip * 8;
    if (base >= M) return;
    long nend = base + 8; if (nend > M) nend = M;
    float sc[4], shv[4];
#pragma unroll
    for (int j = 0; j < 4; ++j) {
        float s = 0.f, q = 0.f;
#pragma unroll
        for (int r = 0; r < 8; ++r) {
            s += stats[(r << 8) + c + j];
            q += stats[(r << 8) + D + c + j];
        }
        float mean = s * invM;
        float sv = rsqrtf(q * invM - mean * mean + 1e-5f) * gamma[c + j];
        sc[j] = sv;
        shv[j] = beta[c + j] - mean * sv;
    }
    float wl = fw[layer];
    int cur = -1;
    float a0 = 0.f, a1 = 0.f, a2 = 0.f, a3 = 0.f;
    for (long node = base; node < nend; ++node) {
        ushort4 v = *(const ushort4*)(y + (node << 7) + c);
        float h0 = fmaxf(0.f, fmaf(bf2f(v.x), sc[0], shv[0]));
        float h1 = fmaxf(0.f, fmaf(bf2f(v.y), sc[1], shv[1]));
        float h2 = fmaxf(0.f, fmaf(bf2f(v.z), sc[2], shv[2]));
        float h3 = fmaxf(0.f, fmaf(bf2f(v.w), sc[3], shv[3]));
        ushort4 r;
        r.x = f2bf(h0); r.y = f2bf(h1); r.z = f2bf(h2); r.w = f2bf(h3);
        *(ushort4*)(hout + (node << 7) + c) = r;
        int gid = gids[node];
        if (gid != cur) {
            if (cur >= 0) {
                float* gp = gacc + ((size_t)cur << 7) + c;
                atomicAdd(gp, wl * a0); atomicAdd(gp + 1, wl * a1);
                atomicAdd(gp + 2, wl * a2); atomicAdd(gp + 3, wl * a3);
            }
            cur = gid;
            a0 = a1 = a2 = a3 = 0.f;
        }
        a0 += h0; a1 += h1; a2 += h2; a3 += h3;
    }
    if (cur >= 0) {
        float* gp = gacc + ((size_t)cur << 7) + c;
        atomicAdd(gp, wl * a0); atomicAdd(gp + 1, wl * a1);
        atomicAdd(gp + 2, wl * a2); atomicAdd(gp + 3, wl * a3);
    }
}

// ---------------- final: out = gacc(Gx128) @ Wp(128x10) + bp ----------------
__global__ void k_final(const float* __restrict__ gacc, const float* __restrict__ Wp,
                        const float* __restrict__ bp, float* __restrict__ out) {
    __shared__ float w[D * DOUT];
    __shared__ float bb[DOUT];
    int t = threadIdx.x;
    for (int i = t; i < D * DOUT; i += blockDim.x) w[i] = Wp[i];
    if (t < DOUT) bb[t] = bp[t];
    __syncthreads();
    float acc[DOUT];
#pragma unroll
    for (int o = 0; o < DOUT; ++o) acc[o] = bb[o];
    for (int k = 0; k < D; ++k) {
        float a = gacc[(size_t)t * D + k];
#pragma unroll
        for (int o = 0; o < DOUT; ++o) acc[o] += a * w[k * DOUT + o];
    }
#pragma unroll
    for (int o = 0; o < DOUT; ++o) out[(size_t)t * DOUT + o] = acc[o];
}

extern "C" void kernel_launch(void* const* d_in, const int* in_sizes, int n_in,
                              void* d_out, int out_size, void* d_ws, size_t ws_size,
                              hipStream_t stream) {
    const float* x    = (const float*)d_in[0];
    const int* esrc   = (const int*)d_in[1];
    const int* edst   = (const int*)d_in[2];
    const int* gids   = (const int*)d_in[3];
    const float* eps  = (const float*)d_in[4];
    const float* fw   = (const float*)d_in[5];
    const float* W1   = (const float*)d_in[6];
    const float* b1   = (const float*)d_in[7];
    const float* g1   = (const float*)d_in[8];
    const float* bt1  = (const float*)d_in[9];
    const float* W2   = (const float*)d_in[10];
    const float* b2   = (const float*)d_in[11];
    const float* g2   = (const float*)d_in[12];
    const float* bt2  = (const float*)d_in[13];
    const float* Wp   = (const float*)d_in[14];
    const float* bp   = (const float*)d_in[15];
    float* out        = (float*)d_out;

    const int M = in_sizes[3];     // 100000 nodes
    const int E = in_sizes[1];     // 1600000 edges
    const int L = in_sizes[4];     // 4 layers
    const int G = out_size / DOUT; // 256 graphs
    const int nb  = (M + 127) >> 7;           // buckets of 128 dst nodes (782)
    const int Mpad = nb << 7;
    const int nbk = (E + 2047) >> 11;         // 2K-edge chunks (782)
    const int nbh = nb >> 1;                  // half grid for agg split
    const float invM = 1.0f / (float)M;

    char* ws = (char*)d_ws;
    u16* bufP  = (u16*)ws;  ws += (size_t)Mpad * D * 2;   // pooled bf16
    u16* bufT  = (u16*)ws;  ws += (size_t)Mpad * D * 2;   // MLP temp bf16
    u16* bufH  = (u16*)ws;  ws += (size_t)Mpad * D * 2;   // hidden bf16
    int* pairs = (int*)ws;  ws += (size_t)nb * 4096 * 4;  // packed (src<<7)|(dst&127)
    int* cnts  = (int*)ws;  ws += (size_t)nbk * 1024 * 4; // per-(chunk,bucket) bases
    int* btot  = (int*)ws;  ws += 1024 * 4;               // bucket totals
    bf16x8* wswz = (bf16x8*)ws; ws += (size_t)2 * L * 2048 * 16;  // swizzled W
    // contiguous zero region: stats (8 replicas) | gacc
    float* stats = (float*)ws; ws += (size_t)L * 4096 * 4;
    float* gacc  = (float*)ws; ws += (size_t)G * D * 4;

    int zbytes = L * 4096 * 4 + G * D * 4;
    int n4 = zbytes / 16;
    k_zero<<<(n4 + 255) / 256, 256, 0, stream>>>((float4*)stats, n4);

    k_prepw<<<2 * L * 8, 256, 0, stream>>>(W1, W2, wswz, L);
    k_hist<<<nbk, 256, 0, stream>>>(edst, cnts, E, nb);
    k_off<<<(nb + 3) / 4, 256, 0, stream>>>(cnts, btot, nbk, nb);
    k_scat<<<nbk, 256, 0, stream>>>(esrc, edst, cnts, pairs, E, nb);
    k_cvt<<<(Mpad * (D / 4) + 255) / 256, 256, 0, stream>>>(x, bufH, M, Mpad);

    int gemm_grid = Mpad / 64;
    int pool_grid = (M + 63) / 64;
    for (int l = 0; l < L; ++l) {
        float* st1 = stats + (size_t)l * 4096;
        float* st2 = st1 + 2048;
        k_agg<<<nbh, 512, 0, stream>>>(bufH, pairs, btot, eps, l, bufP, M, Mpad, 0);
        k_agg<<<nb - nbh, 512, 0, stream>>>(bufH, pairs, btot, eps, l, bufP, M, Mpad, nbh);
        k_gemm_bf<<<gemm_grid, 256, 0, stream>>>(bufP, bufT, wswz + (size_t)l * 2048,
                                                 b1 + (size_t)l * D, st1, M);
        k_gemm_bn<<<gemm_grid, 256, 0, stream>>>(bufT, wswz + (size_t)(L + l) * 2048,
                                                 b2 + (size_t)l * D, st1,
                                                 g1 + (size_t)l * D, bt1 + (size_t)l * D,
                                                 st2, invM, M);
        k_bn2pool<<<pool_grid, 256, 0, stream>>>(bufT, st2, g2 + (size_t)l * D,
                                                 bt2 + (size_t)l * D, gids, fw, l,
                                                 bufH, gacc, invM, M);
    }
    k_final<<<1, G, 0, stream>>>(gacc, Wp, bp, out);
}

// Round 10
// 766.194 us; speedup vs baseline: 1.0681x; 1.0120x over previous
//
#include <hip/hip_runtime.h>

#define D 128            // hidden dim
#define DOUT 10
#define CT_STRIDE 152    // C-tile LDS row stride in u16

typedef float f32x4 __attribute__((ext_vector_type(4)));
typedef __bf16 bf16x8 __attribute__((ext_vector_type(8)));
typedef unsigned short u16;

__device__ __forceinline__ float bf2f(u16 u) {
    return __uint_as_float(((unsigned int)u) << 16);
}
__device__ __forceinline__ u16 f2bf(float f) {
    unsigned int u = __float_as_uint(f);
    u += 0x7fffu + ((u >> 16) & 1u);
    return (u16)(u >> 16);
}

// ---------------- zero init (stats | gacc contiguous) ----------------
__global__ void k_zero(float4* __restrict__ p, int n4) {
    int i = blockIdx.x * 256 + threadIdx.x;
    if (i < n4) p[i] = make_float4(0.f, 0.f, 0.f, 0.f);
}

// ---------------- pre-swizzle W1/W2 into MFMA B-fragment order (once per call) -----
__global__ __launch_bounds__(256) void k_prepw(const float* __restrict__ W1,
                                               const float* __restrict__ W2,
                                               bf16x8* __restrict__ wswz, int L) {
    int b = blockIdx.x >> 3;
    const float* W = (b < L) ? (W1 + (size_t)b * D * D)
                             : (W2 + (size_t)(b - L) * D * D);
    bf16x8* o = wswz + (size_t)b * 2048;
    int idx = ((blockIdx.x & 7) << 8) + threadIdx.x;   // 0..2047
    int lane_s = idx & 63;
    int f = idx >> 6;
    int n = ((f >> 2) << 4) | (lane_s & 15);
    int kb = ((f & 3) << 5) | ((lane_s >> 4) << 3);
    bf16x8 fr;
#pragma unroll
    for (int j = 0; j < 8; ++j) fr[j] = (__bf16)W[(kb + j) * D + n];
    o[idx] = fr;
}

// ============ bucketing: 2048-edge chunks, deterministic two-level =================
__global__ __launch_bounds__(256) void k_hist(const int* __restrict__ dst,
                                              int* __restrict__ cnts, int E, int nb) {
    __shared__ int hist[1024];
    int tid = threadIdx.x;
    for (int i = tid; i < nb; i += 256) hist[i] = 0;
    __syncthreads();
    int e0 = blockIdx.x << 11;
    int e1 = e0 + 2048; if (e1 > E) e1 = E;
    for (int e = e0 + tid; e < e1; e += 256) atomicAdd(&hist[dst[e] >> 7], 1);
    __syncthreads();
    for (int i = tid; i < nb; i += 256) cnts[(blockIdx.x << 10) + i] = hist[i];
}

// per-bucket exclusive scan across chunk-blocks; one WAVE per bucket, shuffle scan.
__global__ __launch_bounds__(256) void k_off(int* __restrict__ cnts,
                                             int* __restrict__ btot,
                                             int nbk, int nb) {
    int wave = threadIdx.x >> 6, lane = threadIdx.x & 63;
    int b = blockIdx.x * 4 + wave;
    if (b >= nb) return;
    int carry = 0;
    for (int base = 0; base < nbk; base += 64) {
        int idx = base + lane;
        int orig = (idx < nbk) ? cnts[(idx << 10) + b] : 0;
        int c = orig;
#pragma unroll
        for (int off = 1; off < 64; off <<= 1) {
            int v = __shfl_up(c, off);
            if (lane >= off) c += v;
        }
        if (idx < nbk) cnts[(idx << 10) + b] = carry + (c - orig);  // exclusive
        carry += __shfl(c, 63);
    }
    if (lane == 0) btot[b] = carry;
}

__global__ __launch_bounds__(256) void k_scat(const int* __restrict__ src,
                                              const int* __restrict__ dst,
                                              const int* __restrict__ cnts,
                                              int* __restrict__ pairs, int E, int nb) {
    __shared__ int lbase[1024];
    __shared__ int lcur[1024];
    int tid = threadIdx.x;
    for (int i = tid; i < nb; i += 256) {
        lbase[i] = cnts[(blockIdx.x << 10) + i];
        lcur[i] = 0;
    }
    __syncthreads();
    int e0 = blockIdx.x << 11;
    int e1 = e0 + 2048; if (e1 > E) e1 = E;
    for (int e = e0 + tid; e < e1; e += 256) {
        int d = dst[e];
        int b = d >> 7;
        int pos = lbase[b] + atomicAdd(&lcur[b], 1);
        if (pos < 4096) pairs[(b << 12) + pos] = (src[e] << 7) | (d & 127);
    }
}

// ---------------- x fp32 -> bf16 (padded rows zeroed) ----------------
__global__ void k_cvt(const float* __restrict__ x, u16* __restrict__ o,
                      int M, int Mpad) {
    long e = ((long)blockIdx.x * 256 + threadIdx.x) * 4;
    if (e >= (long)Mpad * D) return;
    ushort4 r;
    if (e < (long)M * D) {
        float4 v = *(const float4*)(x + e);
        r.x = f2bf(v.x); r.y = f2bf(v.y); r.z = f2bf(v.z); r.w = f2bf(v.w);
    } else {
        r = make_ushort4(0, 0, 0, 0);
    }
    *(ushort4*)(o + e) = r;
}

// ---------------- bucket aggregation: local CSR in LDS, register accumulation -----
__global__ __launch_bounds__(512) void k_agg(
        const u16* __restrict__ h, const int* __restrict__ pairs,
        const int* __restrict__ bcnt, const float* __restrict__ eps, int layer,
        u16* __restrict__ out, int M, int Mpad, int b0) {
    __shared__ int lcnt[128];
    __shared__ int loff[128];
    __shared__ int lcur[128];
    __shared__ int ledge[4096];
    int tid = threadIdx.x;
    if (tid < 128) lcnt[tid] = 0;
    __syncthreads();

    int b = b0 + blockIdx.x;
    int cnt = bcnt[b];
    if (cnt > 4096) cnt = 4096;
    const int* pb = pairs + ((size_t)b << 12);

    for (int e = tid; e < cnt; e += 512)
        atomicAdd(&lcnt[pb[e] & 127], 1);
    __syncthreads();

    if (tid < 128) loff[tid] = lcnt[tid];
    __syncthreads();
    for (int off = 1; off < 128; off <<= 1) {
        int v = 0;
        if (tid < 128 && tid >= off) v = loff[tid - off];
        __syncthreads();
        if (tid < 128) loff[tid] += v;
        __syncthreads();
    }
    if (tid < 128) lcur[tid] = loff[tid] - lcnt[tid];
    __syncthreads();

    for (int e = tid; e < cnt; e += 512) {
        int p = pb[e];
        int pos = atomicAdd(&lcur[p & 127], 1);
        ledge[pos] = p >> 7;
    }
    __syncthreads();

    float e1 = 1.0f + eps[layer];
    int grp = tid >> 5;
    int c = (tid & 31) << 2;
    for (int pass = 0; pass < 8; ++pass) {
        int row = (pass << 4) + grp;
        int node = (b << 7) + row;
        if (node >= Mpad) continue;
        u16* op = out + ((size_t)node << 7) + c;
        if (node >= M) { *(ushort4*)op = make_ushort4(0, 0, 0, 0); continue; }
        ushort4 sv = *(const ushort4*)(h + ((size_t)node << 7) + c);
        float a0 = e1 * bf2f(sv.x), a1 = e1 * bf2f(sv.y);
        float a2 = e1 * bf2f(sv.z), a3 = e1 * bf2f(sv.w);
        int dd = lcnt[row];
        int s = loff[row] - dd;
        int i = 0;
        for (; i + 8 <= dd; i += 8) {
            int n0 = ledge[s + i],     n1 = ledge[s + i + 1];
            int n2 = ledge[s + i + 2], n3 = ledge[s + i + 3];
            int n4 = ledge[s + i + 4], n5 = ledge[s + i + 5];
            int n6 = ledge[s + i + 6], n7 = ledge[s + i + 7];
            ushort4 u0 = *(const ushort4*)(h + ((size_t)n0 << 7) + c);
            ushort4 u1 = *(const ushort4*)(h + ((size_t)n1 << 7) + c);
            ushort4 u2 = *(const ushort4*)(h + ((size_t)n2 << 7) + c);
            ushort4 u3 = *(const ushort4*)(h + ((size_t)n3 << 7) + c);
            ushort4 u4 = *(const ushort4*)(h + ((size_t)n4 << 7) + c);
            ushort4 u5 = *(const ushort4*)(h + ((size_t)n5 << 7) + c);
            ushort4 u6 = *(const ushort4*)(h + ((size_t)n6 << 7) + c);
            ushort4 u7 = *(const ushort4*)(h + ((size_t)n7 << 7) + c);
            a0 += bf2f(u0.x) + bf2f(u1.x) + bf2f(u2.x) + bf2f(u3.x)
                + bf2f(u4.x) + bf2f(u5.x) + bf2f(u6.x) + bf2f(u7.x);
            a1 += bf2f(u0.y) + bf2f(u1.y) + bf2f(u2.y) + bf2f(u3.y)
                + bf2f(u4.y) + bf2f(u5.y) + bf2f(u6.y) + bf2f(u7.y);
            a2 += bf2f(u0.z) + bf2f(u1.z) + bf2f(u2.z) + bf2f(u3.z)
                + bf2f(u4.z) + bf2f(u5.z) + bf2f(u6.z) + bf2f(u7.z);
            a3 += bf2f(u0.w) + bf2f(u1.w) + bf2f(u2.w) + bf2f(u3.w)
                + bf2f(u4.w) + bf2f(u5.w) + bf2f(u6.w) + bf2f(u7.w);
        }
        for (; i + 4 <= dd; i += 4) {
            int n0 = ledge[s + i],     n1 = ledge[s + i + 1];
            int n2 = ledge[s + i + 2], n3 = ledge[s + i + 3];
            ushort4 u0 = *(const ushort4*)(h + ((size_t)n0 << 7) + c);
            ushort4 u1 = *(const ushort4*)(h + ((size_t)n1 << 7) + c);
            ushort4 u2 = *(const ushort4*)(h + ((size_t)n2 << 7) + c);
            ushort4 u3 = *(const ushort4*)(h + ((size_t)n3 << 7) + c);
            a0 += bf2f(u0.x) + bf2f(u1.x) + bf2f(u2.x) + bf2f(u3.x);
            a1 += bf2f(u0.y) + bf2f(u1.y) + bf2f(u2.y) + bf2f(u3.y);
            a2 += bf2f(u0.z) + bf2f(u1.z) + bf2f(u2.z) + bf2f(u3.z);
            a3 += bf2f(u0.w) + bf2f(u1.w) + bf2f(u2.w) + bf2f(u3.w);
        }
        for (; i < dd; ++i) {
            int n0 = ledge[s + i];
            ushort4 u0 = *(const ushort4*)(h + ((size_t)n0 << 7) + c);
            a0 += bf2f(u0.x); a1 += bf2f(u0.y); a2 += bf2f(u0.z); a3 += bf2f(u0.w);
        }
        ushort4 r;
        r.x = f2bf(a0); r.y = f2bf(a1); r.z = f2bf(a2); r.w = f2bf(a3);
        *(ushort4*)op = r;
    }
}

// ---------------- GEMM1: 64-row tile, 4 blocks/CU; A-prefetch above W staging ------
__global__ __launch_bounds__(256, 4) void k_gemm_bf(
        const u16* __restrict__ A, u16* __restrict__ O,
        const bf16x8* __restrict__ wz, const float* __restrict__ bias,
        float* __restrict__ stats, int M) {
    __shared__ union { bf16x8 w[2048]; u16 c[64 * CT_STRIDE]; } sh;  // 32 KB
    __shared__ float blds[D], psum[4 * D], psq[4 * D];
    int tid = threadIdx.x;
    int wave = tid >> 6, lane = tid & 63;
    int m = lane & 15, quad = lane >> 4;
    int row0 = blockIdx.x * 64 + wave * 16;

    const u16* ap = A + (size_t)(row0 + m) * D + (quad << 3);
    bf16x8 a[4];
#pragma unroll
    for (int kc = 0; kc < 4; ++kc) a[kc] = *(const bf16x8*)(ap + (kc << 5));

    for (int i = tid; i < 2048; i += 256) sh.w[i] = wz[i];
    if (tid < D) blds[tid] = bias[tid];
    __syncthreads();

    f32x4 z = {0.f, 0.f, 0.f, 0.f};
    f32x4 acc[8];
#pragma unroll
    for (int t = 0; t < 8; ++t) acc[t] = z;

#pragma unroll
    for (int kc = 0; kc < 4; ++kc)
#pragma unroll
        for (int t = 0; t < 8; ++t)
            acc[t] = __builtin_amdgcn_mfma_f32_16x16x32_bf16(
                a[kc], sh.w[(((t << 2) | kc) << 6) | lane], acc[t], 0, 0, 0);
    __syncthreads();   // done reading sh.w

    int lr0 = wave * 16 + (quad << 2);
    int gr0 = blockIdx.x * 64 + lr0;
#pragma unroll
    for (int t = 0; t < 8; ++t) {
        int cch = (t << 4) | m;
        float bc = blds[cch];
        float s = 0.f, q = 0.f;
#pragma unroll
        for (int r = 0; r < 4; ++r) {
            float v = acc[t][r] + bc;
            sh.c[(lr0 + r) * CT_STRIDE + cch] = f2bf(v);
            if (gr0 + r < M) { s += v; q += v * v; }
        }
        s += __shfl_xor(s, 16); s += __shfl_xor(s, 32);
        q += __shfl_xor(q, 16); q += __shfl_xor(q, 32);
        if (quad == 0) { psum[wave * D + cch] = s; psq[wave * D + cch] = q; }
    }
    __syncthreads();

    int mrow = M - blockIdx.x * 64;
#pragma unroll
    for (int i = 0; i < 4; ++i) {
        int idx = (i << 8) + tid;
        int row = idx >> 4, ch8 = (idx & 15) << 3;
        if (row < mrow) {
            float4 v = *(const float4*)&sh.c[row * CT_STRIDE + ch8];
            *(float4*)(O + ((size_t)(blockIdx.x * 64 + row) << 7) + ch8) = v;
        }
    }
    if (tid < D) {
        float s = psum[tid] + psum[D + tid] + psum[2 * D + tid] + psum[3 * D + tid];
        float q = psq[tid] + psq[D + tid] + psq[2 * D + tid] + psq[3 * D + tid];
        float* st = stats + ((blockIdx.x & 7) << 8);
        atomicAdd(&st[tid], s);
        atomicAdd(&st[D + tid], q);
    }
}

// ---------------- GEMM2: BN1+ReLU on the fly -> @W + b, in-place, + stats2 ---------
__global__ __launch_bounds__(256, 4) void k_gemm_bn(
        u16* __restrict__ A, const bf16x8* __restrict__ wz,
        const float* __restrict__ bias, const float* __restrict__ stats_in,
        const float* __restrict__ gamma, const float* __restrict__ beta,
        float* __restrict__ stats_out, float invM, int M) {
    __shared__ union { bf16x8 w[2048]; u16 c[64 * CT_STRIDE]; } sh;
    __shared__ float blds[D], s_sc[D], s_sh[D], psum[4 * D], psq[4 * D];
    int tid = threadIdx.x;
    int wave = tid >> 6, lane = tid & 63;
    int m = lane & 15, quad = lane >> 4;
    int row0 = blockIdx.x * 64 + wave * 16;

    const u16* ap = A + (size_t)(row0 + m) * D + (quad << 3);
    ushort4 p[4][2];
#pragma unroll
    for (int kc = 0; kc < 4; ++kc) {
        p[kc][0] = *(const ushort4*)(ap + (kc << 5));
        p[kc][1] = *(const ushort4*)(ap + (kc << 5) + 4);
    }

    for (int i = tid; i < 2048; i += 256) sh.w[i] = wz[i];
    if (tid < D) {
        float s = 0.f, q = 0.f;
#pragma unroll
        for (int r = 0; r < 8; ++r) {
            s += stats_in[(r << 8) + tid];
            q += stats_in[(r << 8) + D + tid];
        }
        float mean = s * invM;
        float var = q * invM - mean * mean;
        float sc = rsqrtf(var + 1e-5f) * gamma[tid];
        s_sc[tid] = sc;
        s_sh[tid] = beta[tid] - mean * sc;
        blds[tid] = bias[tid];
    }
    __syncthreads();

    f32x4 z = {0.f, 0.f, 0.f, 0.f};
    f32x4 acc[8];
#pragma unroll
    for (int t = 0; t < 8; ++t) acc[t] = z;

#pragma unroll
    for (int kc = 0; kc < 4; ++kc) {
        int kb = (kc << 5) | (quad << 3);
        float4 c0 = *(const float4*)&s_sc[kb];
        float4 c1 = *(const float4*)&s_sc[kb + 4];
        float4 h0 = *(const float4*)&s_sh[kb];
        float4 h1 = *(const float4*)&s_sh[kb + 4];
        ushort4 p0 = p[kc][0], p1 = p[kc][1];
        bf16x8 af;
        af[0] = (__bf16)fmaxf(0.f, fmaf(bf2f(p0.x), c0.x, h0.x));
        af[1] = (__bf16)fmaxf(0.f, fmaf(bf2f(p0.y), c0.y, h0.y));
        af[2] = (__bf16)fmaxf(0.f, fmaf(bf2f(p0.z), c0.z, h0.z));
        af[3] = (__bf16)fmaxf(0.f, fmaf(bf2f(p0.w), c0.w, h0.w));
        af[4] = (__bf16)fmaxf(0.f, fmaf(bf2f(p1.x), c1.x, h1.x));
        af[5] = (__bf16)fmaxf(0.f, fmaf(bf2f(p1.y), c1.y, h1.y));
        af[6] = (__bf16)fmaxf(0.f, fmaf(bf2f(p1.z), c1.z, h1.z));
        af[7] = (__bf16)fmaxf(0.f, fmaf(bf2f(p1.w), c1.w, h1.w));
#pragma unroll
        for (int t = 0; t < 8; ++t)
            acc[t] = __builtin_amdgcn_mfma_f32_16x16x32_bf16(
                af, sh.w[(((t << 2) | kc) << 6) | lane], acc[t], 0, 0, 0);
    }
    __syncthreads();

    int lr0 = wave * 16 + (quad << 2);
    int gr0 = blockIdx.x * 64 + lr0;
#pragma unroll
    for (int t = 0; t < 8; ++t) {
        int cch = (t << 4) | m;
        float bc = blds[cch];
        float s = 0.f, q = 0.f;
#pragma unroll
        for (int r = 0; r < 4; ++r) {
            float v = acc[t][r] + bc;
            sh.c[(lr0 + r) * CT_STRIDE + cch] = f2bf(v);
            if (gr0 + r < M) { s += v; q += v * v; }
        }
        s += __shfl_xor(s, 16); s += __shfl_xor(s, 32);
        q += __shfl_xor(q, 16); q += __shfl_xor(q, 32);
        if (quad == 0) { psum[wave * D + cch] = s; psq[wave * D + cch] = q; }
    }
    __syncthreads();

    int mrow = M - blockIdx.x * 64;
#pragma unroll
    for (int i = 0; i < 4; ++i) {
        int idx = (i << 8) + tid;
        int row = idx >> 4, ch8 = (idx & 15) << 3;
        if (row < mrow) {
            float4 v = *(const float4*)&sh.c[row * CT_STRIDE + ch8];
            *(float4*)(A + ((size_t)(blockIdx.x * 64 + row) << 7) + ch8) = v;
        }
    }
    if (tid < D) {
        float s = psum[tid] + psum[D + tid] + psum[2 * D + tid] + psum[3 * D + tid];
        float q = psq[tid] + psq[D + tid] + psq[2 * D + tid] + psq[3 * D + tid];
        float* st = stats_out + ((blockIdx.x & 7) << 8);
        atomicAdd(&st[tid], s);
        atomicAdd(&st[D + tid], q);
    }
}

// ---------------- BN2 + ReLU -> bf16 h, + fused weighted graph pooling -------------
// Round-10 rewrite: stats reduced once per block into LDS; all 8 row loads + gid
// loads batched upfront (independent, one latency round); pooling from registers.
__global__ __launch_bounds__(256) void k_bn2pool(
        const u16* __restrict__ y, const float* __restrict__ stats,
        const float* __restrict__ gamma, const float* __restrict__ beta,
        const int* __restrict__ gids, const float* __restrict__ fw,
        int layer, u16* __restrict__ hout, float* __restrict__ gacc,
        float invM, int M) {
    __shared__ float s_sc[D], s_sh[D];
    int t = threadIdx.x;
    if (t < D) {
        float s = 0.f, q = 0.f;
#pragma unroll
        for (int r = 0; r < 8; ++r) {
            s += stats[(r << 8) + t];
            q += stats[(r << 8) + D + t];
        }
        float mean = s * invM;
        float sv = rsqrtf(q * invM - mean * mean + 1e-5f) * gamma[t];
        s_sc[t] = sv;
        s_sh[t] = beta[t] - mean * sv;
    }
    __syncthreads();

    int c = (t & 31) << 2;
    int strip = t >> 5;
    long base = (long)blockIdx.x * 64 + (long)strip * 8;
    if (base >= M) return;
    float4 sc4 = *(const float4*)&s_sc[c];
    float4 sh4 = *(const float4*)&s_sh[c];

    // batched independent loads (rows up to Mpad exist in the padded ws buffer)
    ushort4 v[8];
#pragma unroll
    for (int r = 0; r < 8; ++r)
        v[r] = *(const ushort4*)(y + ((base + r) << 7) + c);
    long gmax = (long)M - 1;
    int g[8];
#pragma unroll
    for (int r = 0; r < 8; ++r) {
        long idx = base + r;
        g[r] = gids[idx > gmax ? gmax : idx];
    }

    float h0[8], h1[8], h2[8], h3[8];
#pragma unroll
    for (int r = 0; r < 8; ++r) {
        h0[r] = fmaxf(0.f, fmaf(bf2f(v[r].x), sc4.x, sh4.x));
        h1[r] = fmaxf(0.f, fmaf(bf2f(v[r].y), sc4.y, sh4.y));
        h2[r] = fmaxf(0.f, fmaf(bf2f(v[r].z), sc4.z, sh4.z));
        h3[r] = fmaxf(0.f, fmaf(bf2f(v[r].w), sc4.w, sh4.w));
    }
#pragma unroll
    for (int r = 0; r < 8; ++r) {
        if (base + r < M) {
            ushort4 o;
            o.x = f2bf(h0[r]); o.y = f2bf(h1[r]);
            o.z = f2bf(h2[r]); o.w = f2bf(h3[r]);
            *(ushort4*)(hout + ((base + r) << 7) + c) = o;
        }
    }

    float wl = fw[layer];
    int cur = -1;
    float a0 = 0.f, a1 = 0.f, a2 = 0.f, a3 = 0.f;
#pragma unroll
    for (int r = 0; r < 8; ++r) {
        if (base + r < M) {
            if (g[r] != cur) {
                if (cur >= 0) {
                    float* gp = gacc + ((size_t)cur << 7) + c;
                    atomicAdd(gp, wl * a0); atomicAdd(gp + 1, wl * a1);
                    atomicAdd(gp + 2, wl * a2); atomicAdd(gp + 3, wl * a3);
                }
                cur = g[r];
                a0 = a1 = a2 = a3 = 0.f;
            }
            a0 += h0[r]; a1 += h1[r]; a2 += h2[r]; a3 += h3[r];
        }
    }
    if (cur >= 0) {
        float* gp = gacc + ((size_t)cur << 7) + c;
        atomicAdd(gp, wl * a0); atomicAdd(gp + 1, wl * a1);
        atomicAdd(gp + 2, wl * a2); atomicAdd(gp + 3, wl * a3);
    }
}

// ---------------- final: out = gacc(Gx128) @ Wp(128x10) + bp ----------------
__global__ void k_final(const float* __restrict__ gacc, const float* __restrict__ Wp,
                        const float* __restrict__ bp, float* __restrict__ out) {
    __shared__ float w[D * DOUT];
    __shared__ float bb[DOUT];
    int t = threadIdx.x;
    for (int i = t; i < D * DOUT; i += blockDim.x) w[i] = Wp[i];
    if (t < DOUT) bb[t] = bp[t];
    __syncthreads();
    float acc[DOUT];
#pragma unroll
    for (int o = 0; o < DOUT; ++o) acc[o] = bb[o];
    for (int k = 0; k < D; ++k) {
        float a = gacc[(size_t)t * D + k];
#pragma unroll
        for (int o = 0; o < DOUT; ++o) acc[o] += a * w[k * DOUT + o];
    }
#pragma unroll
    for (int o = 0; o < DOUT; ++o) out[(size_t)t * DOUT + o] = acc[o];
}

extern "C" void kernel_launch(void* const* d_in, const int* in_sizes, int n_in,
                              void* d_out, int out_size, void* d_ws, size_t ws_size,
                              hipStream_t stream) {
    const float* x    = (const float*)d_in[0];
    const int* esrc   = (const int*)d_in[1];
    const int* edst   = (const int*)d_in[2];
    const int* gids   = (const int*)d_in[3];
    const float* eps  = (const float*)d_in[4];
    const float* fw   = (const float*)d_in[5];
    const float* W1   = (const float*)d_in[6];
    const float* b1   = (const float*)d_in[7];
    const float* g1   = (const float*)d_in[8];
    const float* bt1  = (const float*)d_in[9];
    const float* W2   = (const float*)d_in[10];
    const float* b2   = (const float*)d_in[11];
    const float* g2   = (const float*)d_in[12];
    const float* bt2  = (const float*)d_in[13];
    const float* Wp   = (const float*)d_in[14];
    const float* bp   = (const float*)d_in[15];
    float* out        = (float*)d_out;

    const int M = in_sizes[3];     // 100000 nodes
    const int E = in_sizes[1];     // 1600000 edges
    const int L = in_sizes[4];     // 4 layers
    const int G = out_size / DOUT; // 256 graphs
    const int nb  = (M + 127) >> 7;           // buckets of 128 dst nodes (782)
    const int Mpad = nb << 7;
    const int nbk = (E + 2047) >> 11;         // 2K-edge chunks (782)
    const int nbh = nb >> 1;                  // half grid for agg split
    const float invM = 1.0f / (float)M;

    char* ws = (char*)d_ws;
    u16* bufP  = (u16*)ws;  ws += (size_t)Mpad * D * 2;   // pooled bf16
    u16* bufT  = (u16*)ws;  ws += (size_t)Mpad * D * 2;   // MLP temp bf16
    u16* bufH  = (u16*)ws;  ws += (size_t)Mpad * D * 2;   // hidden bf16
    int* pairs = (int*)ws;  ws += (size_t)nb * 4096 * 4;  // packed (src<<7)|(dst&127)
    int* cnts  = (int*)ws;  ws += (size_t)nbk * 1024 * 4; // per-(chunk,bucket) bases
    int* btot  = (int*)ws;  ws += 1024 * 4;               // bucket totals
    bf16x8* wswz = (bf16x8*)ws; ws += (size_t)2 * L * 2048 * 16;  // swizzled W
    // contiguous zero region: stats (8 replicas) | gacc
    float* stats = (float*)ws; ws += (size_t)L * 4096 * 4;
    float* gacc  = (float*)ws; ws += (size_t)G * D * 4;

    int zbytes = L * 4096 * 4 + G * D * 4;
    int n4 = zbytes / 16;
    k_zero<<<(n4 + 255) / 256, 256, 0, stream>>>((float4*)stats, n4);

    k_prepw<<<2 * L * 8, 256, 0, stream>>>(W1, W2, wswz, L);
    k_hist<<<nbk, 256, 0, stream>>>(edst, cnts, E, nb);
    k_off<<<(nb + 3) / 4, 256, 0, stream>>>(cnts, btot, nbk, nb);
    k_scat<<<nbk, 256, 0, stream>>>(esrc, edst, cnts, pairs, E, nb);
    k_cvt<<<(Mpad * (D / 4) + 255) / 256, 256, 0, stream>>>(x, bufH, M, Mpad);

    int gemm_grid = Mpad / 64;
    int pool_grid = (M + 63) / 64;
    for (int l = 0; l < L; ++l) {
        float* st1 = stats + (size_t)l * 4096;
        float* st2 = st1 + 2048;
        k_agg<<<nbh, 512, 0, stream>>>(bufH, pairs, btot, eps, l, bufP, M, Mpad, 0);
        k_agg<<<nb - nbh, 512, 0, stream>>>(bufH, pairs, btot, eps, l, bufP, M, Mpad, nbh);
        k_gemm_bf<<<gemm_grid, 256, 0, stream>>>(bufP, bufT, wswz + (size_t)l * 2048,
                                                 b1 + (size_t)l * D, st1, M);
        k_gemm_bn<<<gemm_grid, 256, 0, stream>>>(bufT, wswz + (size_t)(L + l) * 2048,
                                                 b2 + (size_t)l * D, st1,
                                                 g1 + (size_t)l * D, bt1 + (size_t)l * D,
                                                 st2, invM, M);
        k_bn2pool<<<pool_grid, 256, 0, stream>>>(bufT, st2, g2 + (size_t)l * D,
                                                 bt2 + (size_t)l * D, gids, fw, l,
                                                 bufH, gacc, invM, M);
    }
    k_final<<<1, G, 0, stream>>>(gacc, Wp, bp, out);
}

// Round 11
// 745.255 us; speedup vs baseline: 1.0981x; 1.0281x over previous
//
#include <hip/hip_runtime.h>

#define D 128            // hidden dim
#define DOUT 10
#define CT_STRIDE 152    // C-tile LDS row stride in u16 (gemm_bn)
#define TSTR 136         // fused-kernel tile row stride in u16 (272 B, 16B-aligned)

typedef float f32x4 __attribute__((ext_vector_type(4)));
typedef __bf16 bf16x8 __attribute__((ext_vector_type(8)));
typedef unsigned short u16;

__device__ __forceinline__ float bf2f(u16 u) {
    return __uint_as_float(((unsigned int)u) << 16);
}
__device__ __forceinline__ u16 f2bf(float f) {
    unsigned int u = __float_as_uint(f);
    u += 0x7fffu + ((u >> 16) & 1u);
    return (u16)(u >> 16);
}

// ---------------- zero init (stats | gacc contiguous) ----------------
__global__ void k_zero(float4* __restrict__ p, int n4) {
    int i = blockIdx.x * 256 + threadIdx.x;
    if (i < n4) p[i] = make_float4(0.f, 0.f, 0.f, 0.f);
}

// ---------------- pre-swizzle W1/W2 into MFMA B-fragment order (once per call) -----
__global__ __launch_bounds__(256) void k_prepw(const float* __restrict__ W1,
                                               const float* __restrict__ W2,
                                               bf16x8* __restrict__ wswz, int L) {
    int b = blockIdx.x >> 3;
    const float* W = (b < L) ? (W1 + (size_t)b * D * D)
                             : (W2 + (size_t)(b - L) * D * D);
    bf16x8* o = wswz + (size_t)b * 2048;
    int idx = ((blockIdx.x & 7) << 8) + threadIdx.x;   // 0..2047
    int lane_s = idx & 63;
    int f = idx >> 6;
    int n = ((f >> 2) << 4) | (lane_s & 15);
    int kb = ((f & 3) << 5) | ((lane_s >> 4) << 3);
    bf16x8 fr;
#pragma unroll
    for (int j = 0; j < 8; ++j) fr[j] = (__bf16)W[(kb + j) * D + n];
    o[idx] = fr;
}

// ============ bucketing: 2048-edge chunks, deterministic two-level =================
__global__ __launch_bounds__(256) void k_hist(const int* __restrict__ dst,
                                              int* __restrict__ cnts, int E, int nb) {
    __shared__ int hist[1024];
    int tid = threadIdx.x;
    for (int i = tid; i < nb; i += 256) hist[i] = 0;
    __syncthreads();
    int e0 = blockIdx.x << 11;
    int e1 = e0 + 2048; if (e1 > E) e1 = E;
    for (int e = e0 + tid; e < e1; e += 256) atomicAdd(&hist[dst[e] >> 7], 1);
    __syncthreads();
    for (int i = tid; i < nb; i += 256) cnts[(blockIdx.x << 10) + i] = hist[i];
}

__global__ __launch_bounds__(256) void k_off(int* __restrict__ cnts,
                                             int* __restrict__ btot,
                                             int nbk, int nb) {
    int wave = threadIdx.x >> 6, lane = threadIdx.x & 63;
    int b = blockIdx.x * 4 + wave;
    if (b >= nb) return;
    int carry = 0;
    for (int base = 0; base < nbk; base += 64) {
        int idx = base + lane;
        int orig = (idx < nbk) ? cnts[(idx << 10) + b] : 0;
        int c = orig;
#pragma unroll
        for (int off = 1; off < 64; off <<= 1) {
            int v = __shfl_up(c, off);
            if (lane >= off) c += v;
        }
        if (idx < nbk) cnts[(idx << 10) + b] = carry + (c - orig);  // exclusive
        carry += __shfl(c, 63);
    }
    if (lane == 0) btot[b] = carry;
}

__global__ __launch_bounds__(256) void k_scat(const int* __restrict__ src,
                                              const int* __restrict__ dst,
                                              const int* __restrict__ cnts,
                                              int* __restrict__ pairs, int E, int nb) {
    __shared__ int lbase[1024];
    __shared__ int lcur[1024];
    int tid = threadIdx.x;
    for (int i = tid; i < nb; i += 256) {
        lbase[i] = cnts[(blockIdx.x << 10) + i];
        lcur[i] = 0;
    }
    __syncthreads();
    int e0 = blockIdx.x << 11;
    int e1 = e0 + 2048; if (e1 > E) e1 = E;
    for (int e = e0 + tid; e < e1; e += 256) {
        int d = dst[e];
        int b = d >> 7;
        int pos = lbase[b] + atomicAdd(&lcur[b], 1);
        if (pos < 4096) pairs[(b << 12) + pos] = (src[e] << 7) | (d & 127);
    }
}

// ---------------- x fp32 -> bf16 (padded rows zeroed) ----------------
__global__ void k_cvt(const float* __restrict__ x, u16* __restrict__ o,
                      int M, int Mpad) {
    long e = ((long)blockIdx.x * 256 + threadIdx.x) * 4;
    if (e >= (long)Mpad * D) return;
    ushort4 r;
    if (e < (long)M * D) {
        float4 v = *(const float4*)(x + e);
        r.x = f2bf(v.x); r.y = f2bf(v.y); r.z = f2bf(v.z); r.w = f2bf(v.w);
    } else {
        r = make_ushort4(0, 0, 0, 0);
    }
    *(ushort4*)(o + e) = r;
}

// ======== FUSED aggregation + GEMM1(+bias) + BN1-stats =============================
// One block per 128-dst bucket (512 thr = 8 waves). Phases:
//  A: CSR build in LDS + W/bias staging.  B: gather into registers.
//  C: registers -> LDS bf16 tile (CSR space reused) -> MFMA A-frags -> acc.
//  D: epilogue: C-tile via LDS (tile space reused), stats, coalesced stores.
__global__ __launch_bounds__(512, 4) void k_aggemm(
        const u16* __restrict__ h, const int* __restrict__ pairs,
        const int* __restrict__ bcnt, const float* __restrict__ eps, int layer,
        const bf16x8* __restrict__ wz, const float* __restrict__ bias,
        u16* __restrict__ O, float* __restrict__ stats, int M, int b0) {
    __shared__ union UA {
        struct { int lcnt[128]; int loff[128]; int lcur[128]; int ledge[4096]; } csr;
        u16 tile[128 * TSTR];   // pooled bf16 tile, then C-tile (34.8 KB)
    } shA;
    __shared__ bf16x8 shW[2048];           // 32 KB, fragment order
    __shared__ float blds[D], psum[8 * D], psq[8 * D];
    int tid = threadIdx.x;

    // ---- phase A: CSR build; W/bias staged concurrently ----
    if (tid < 128) shA.csr.lcnt[tid] = 0;
    for (int i = tid; i < 2048; i += 512) shW[i] = wz[i];
    if (tid < D) blds[tid] = bias[tid];
    __syncthreads();

    int b = b0 + blockIdx.x;
    int cnt = bcnt[b];
    if (cnt > 4096) cnt = 4096;
    const int* pb = pairs + ((size_t)b << 12);

    for (int e = tid; e < cnt; e += 512)
        atomicAdd(&shA.csr.lcnt[pb[e] & 127], 1);
    __syncthreads();
    if (tid < 128) shA.csr.loff[tid] = shA.csr.lcnt[tid];
    __syncthreads();
    for (int off = 1; off < 128; off <<= 1) {
        int v = 0;
        if (tid < 128 && tid >= off) v = shA.csr.loff[tid - off];
        __syncthreads();
        if (tid < 128) shA.csr.loff[tid] += v;
        __syncthreads();
    }
    if (tid < 128) shA.csr.lcur[tid] = shA.csr.loff[tid] - shA.csr.lcnt[tid];
    __syncthreads();
    for (int e = tid; e < cnt; e += 512) {
        int p = pb[e];
        int pos = atomicAdd(&shA.csr.lcur[p & 127], 1);
        shA.csr.ledge[pos] = p >> 7;
    }
    __syncthreads();

    // ---- phase B: gather into registers (8 rows per thread-group position) ----
    float e1 = 1.0f + eps[layer];
    int grp = tid >> 5;
    int c = (tid & 31) << 2;
    float r0[8], r1[8], r2[8], r3[8];
    for (int pass = 0; pass < 8; ++pass) {
        int row = (pass << 4) + grp;
        int node = (b << 7) + row;
        float a0 = 0.f, a1 = 0.f, a2 = 0.f, a3 = 0.f;
        if (node < M) {
            ushort4 sv = *(const ushort4*)(h + ((size_t)node << 7) + c);
            a0 = e1 * bf2f(sv.x); a1 = e1 * bf2f(sv.y);
            a2 = e1 * bf2f(sv.z); a3 = e1 * bf2f(sv.w);
            int dd = shA.csr.lcnt[row];
            int s = shA.csr.loff[row] - dd;
            int i = 0;
            for (; i + 8 <= dd; i += 8) {
                int n0 = shA.csr.ledge[s + i],     n1 = shA.csr.ledge[s + i + 1];
                int n2 = shA.csr.ledge[s + i + 2], n3 = shA.csr.ledge[s + i + 3];
                int n4 = shA.csr.ledge[s + i + 4], n5 = shA.csr.ledge[s + i + 5];
                int n6 = shA.csr.ledge[s + i + 6], n7 = shA.csr.ledge[s + i + 7];
                ushort4 u0 = *(const ushort4*)(h + ((size_t)n0 << 7) + c);
                ushort4 u1 = *(const ushort4*)(h + ((size_t)n1 << 7) + c);
                ushort4 u2 = *(const ushort4*)(h + ((size_t)n2 << 7) + c);
                ushort4 u3 = *(const ushort4*)(h + ((size_t)n3 << 7) + c);
                ushort4 u4 = *(const ushort4*)(h + ((size_t)n4 << 7) + c);
                ushort4 u5 = *(const ushort4*)(h + ((size_t)n5 << 7) + c);
                ushort4 u6 = *(const ushort4*)(h + ((size_t)n6 << 7) + c);
                ushort4 u7 = *(const ushort4*)(h + ((size_t)n7 << 7) + c);
                a0 += bf2f(u0.x) + bf2f(u1.x) + bf2f(u2.x) + bf2f(u3.x)
                    + bf2f(u4.x) + bf2f(u5.x) + bf2f(u6.x) + bf2f(u7.x);
                a1 += bf2f(u0.y) + bf2f(u1.y) + bf2f(u2.y) + bf2f(u3.y)
                    + bf2f(u4.y) + bf2f(u5.y) + bf2f(u6.y) + bf2f(u7.y);
                a2 += bf2f(u0.z) + bf2f(u1.z) + bf2f(u2.z) + bf2f(u3.z)
                    + bf2f(u4.z) + bf2f(u5.z) + bf2f(u6.z) + bf2f(u7.z);
                a3 += bf2f(u0.w) + bf2f(u1.w) + bf2f(u2.w) + bf2f(u3.w)
                    + bf2f(u4.w) + bf2f(u5.w) + bf2f(u6.w) + bf2f(u7.w);
            }
            for (; i + 4 <= dd; i += 4) {
                int n0 = shA.csr.ledge[s + i],     n1 = shA.csr.ledge[s + i + 1];
                int n2 = shA.csr.ledge[s + i + 2], n3 = shA.csr.ledge[s + i + 3];
                ushort4 u0 = *(const ushort4*)(h + ((size_t)n0 << 7) + c);
                ushort4 u1 = *(const ushort4*)(h + ((size_t)n1 << 7) + c);
                ushort4 u2 = *(const ushort4*)(h + ((size_t)n2 << 7) + c);
                ushort4 u3 = *(const ushort4*)(h + ((size_t)n3 << 7) + c);
                a0 += bf2f(u0.x) + bf2f(u1.x) + bf2f(u2.x) + bf2f(u3.x);
                a1 += bf2f(u0.y) + bf2f(u1.y) + bf2f(u2.y) + bf2f(u3.y);
                a2 += bf2f(u0.z) + bf2f(u1.z) + bf2f(u2.z) + bf2f(u3.z);
                a3 += bf2f(u0.w) + bf2f(u1.w) + bf2f(u2.w) + bf2f(u3.w);
            }
            for (; i < dd; ++i) {
                int n0 = shA.csr.ledge[s + i];
                ushort4 u0 = *(const ushort4*)(h + ((size_t)n0 << 7) + c);
                a0 += bf2f(u0.x); a1 += bf2f(u0.y); a2 += bf2f(u0.z); a3 += bf2f(u0.w);
            }
        }
        r0[pass] = a0; r1[pass] = a1; r2[pass] = a2; r3[pass] = a3;
    }
    __syncthreads();   // CSR no longer needed; union flips to tile

    // ---- phase C: registers -> bf16 tile; tile -> A-frags; MFMA ----
#pragma unroll
    for (int pass = 0; pass < 8; ++pass) {
        int row = (pass << 4) + grp;
        ushort4 v;
        v.x = f2bf(r0[pass]); v.y = f2bf(r1[pass]);
        v.z = f2bf(r2[pass]); v.w = f2bf(r3[pass]);
        *(ushort4*)&shA.tile[row * TSTR + c] = v;
    }
    __syncthreads();

    int wave = tid >> 6, lane = tid & 63;
    int m = lane & 15, quad = lane >> 4;
    f32x4 z = {0.f, 0.f, 0.f, 0.f};
    f32x4 acc[8];
#pragma unroll
    for (int t = 0; t < 8; ++t) acc[t] = z;
#pragma unroll
    for (int kc = 0; kc < 4; ++kc) {
        bf16x8 af = *(const bf16x8*)&shA.tile[(wave * 16 + m) * TSTR + (kc << 5) + (quad << 3)];
#pragma unroll
        for (int t = 0; t < 8; ++t)
            acc[t] = __builtin_amdgcn_mfma_f32_16x16x32_bf16(
                af, shW[(((t << 2) | kc) << 6) | lane], acc[t], 0, 0, 0);
    }
    __syncthreads();   // done reading tile; reuse as C-tile

    // ---- phase D: epilogue (bias, stats, C via LDS, coalesced stores) ----
    int lr0 = wave * 16 + (quad << 2);
    int gr0 = (b << 7) + lr0;
#pragma unroll
    for (int t = 0; t < 8; ++t) {
        int cch = (t << 4) | m;
        float bc = blds[cch];
        float s = 0.f, q = 0.f;
#pragma unroll
        for (int r = 0; r < 4; ++r) {
            float v = acc[t][r] + bc;
            shA.tile[(lr0 + r) * TSTR + cch] = f2bf(v);
            if (gr0 + r < M) { s += v; q += v * v; }
        }
        s += __shfl_xor(s, 16); s += __shfl_xor(s, 32);
        q += __shfl_xor(q, 16); q += __shfl_xor(q, 32);
        if (quad == 0) { psum[wave * D + cch] = s; psq[wave * D + cch] = q; }
    }
    __syncthreads();

    int mrow = M - (b << 7);
#pragma unroll
    for (int i = 0; i < 4; ++i) {
        int idx = (i << 9) + tid;
        int row = idx >> 4, ch8 = (idx & 15) << 3;
        if (row < mrow) {
            float4 v = *(const float4*)&shA.tile[row * TSTR + ch8];
            *(float4*)(O + (((size_t)(b << 7) + row) << 7) + ch8) = v;
        }
    }
    if (tid < D) {
        float s = 0.f, q = 0.f;
#pragma unroll
        for (int w = 0; w < 8; ++w) { s += psum[w * D + tid]; q += psq[w * D + tid]; }
        float* st = stats + ((b & 7) << 8);
        atomicAdd(&st[tid], s);
        atomicAdd(&st[D + tid], q);
    }
}

// ---------------- GEMM2: BN1+ReLU on the fly -> @W + b, in-place, + stats2 ---------
__global__ __launch_bounds__(256, 4) void k_gemm_bn(
        u16* __restrict__ A, const bf16x8* __restrict__ wz,
        const float* __restrict__ bias, const float* __restrict__ stats_in,
        const float* __restrict__ gamma, const float* __restrict__ beta,
        float* __restrict__ stats_out, float invM, int M) {
    __shared__ union { bf16x8 w[2048]; u16 c[64 * CT_STRIDE]; } sh;
    __shared__ float blds[D], s_sc[D], s_sh[D], psum[4 * D], psq[4 * D];
    int tid = threadIdx.x;
    int wave = tid >> 6, lane = tid & 63;
    int m = lane & 15, quad = lane >> 4;
    int row0 = blockIdx.x * 64 + wave * 16;

    const u16* ap = A + (size_t)(row0 + m) * D + (quad << 3);
    ushort4 p[4][2];
#pragma unroll
    for (int kc = 0; kc < 4; ++kc) {
        p[kc][0] = *(const ushort4*)(ap + (kc << 5));
        p[kc][1] = *(const ushort4*)(ap + (kc << 5) + 4);
    }

    for (int i = tid; i < 2048; i += 256) sh.w[i] = wz[i];
    if (tid < D) {
        float s = 0.f, q = 0.f;
#pragma unroll
        for (int r = 0; r < 8; ++r) {
            s += stats_in[(r << 8) + tid];
            q += stats_in[(r << 8) + D + tid];
        }
        float mean = s * invM;
        float var = q * invM - mean * mean;
        float sc = rsqrtf(var + 1e-5f) * gamma[tid];
        s_sc[tid] = sc;
        s_sh[tid] = beta[tid] - mean * sc;
        blds[tid] = bias[tid];
    }
    __syncthreads();

    f32x4 z = {0.f, 0.f, 0.f, 0.f};
    f32x4 acc[8];
#pragma unroll
    for (int t = 0; t < 8; ++t) acc[t] = z;

#pragma unroll
    for (int kc = 0; kc < 4; ++kc) {
        int kb = (kc << 5) | (quad << 3);
        float4 c0 = *(const float4*)&s_sc[kb];
        float4 c1 = *(const float4*)&s_sc[kb + 4];
        float4 h0 = *(const float4*)&s_sh[kb];
        float4 h1 = *(const float4*)&s_sh[kb + 4];
        ushort4 p0 = p[kc][0], p1 = p[kc][1];
        bf16x8 af;
        af[0] = (__bf16)fmaxf(0.f, fmaf(bf2f(p0.x), c0.x, h0.x));
        af[1] = (__bf16)fmaxf(0.f, fmaf(bf2f(p0.y), c0.y, h0.y));
        af[2] = (__bf16)fmaxf(0.f, fmaf(bf2f(p0.z), c0.z, h0.z));
        af[3] = (__bf16)fmaxf(0.f, fmaf(bf2f(p0.w), c0.w, h0.w));
        af[4] = (__bf16)fmaxf(0.f, fmaf(bf2f(p1.x), c1.x, h1.x));
        af[5] = (__bf16)fmaxf(0.f, fmaf(bf2f(p1.y), c1.y, h1.y));
        af[6] = (__bf16)fmaxf(0.f, fmaf(bf2f(p1.z), c1.z, h1.z));
        af[7] = (__bf16)fmaxf(0.f, fmaf(bf2f(p1.w), c1.w, h1.w));
#pragma unroll
        for (int t = 0; t < 8; ++t)
            acc[t] = __builtin_amdgcn_mfma_f32_16x16x32_bf16(
                af, sh.w[(((t << 2) | kc) << 6) | lane], acc[t], 0, 0, 0);
    }
    __syncthreads();

    int lr0 = wave * 16 + (quad << 2);
    int gr0 = blockIdx.x * 64 + lr0;
#pragma unroll
    for (int t = 0; t < 8; ++t) {
        int cch = (t << 4) | m;
        float bc = blds[cch];
        float s = 0.f, q = 0.f;
#pragma unroll
        for (int r = 0; r < 4; ++r) {
            float v = acc[t][r] + bc;
            sh.c[(lr0 + r) * CT_STRIDE + cch] = f2bf(v);
            if (gr0 + r < M) { s += v; q += v * v; }
        }
        s += __shfl_xor(s, 16); s += __shfl_xor(s, 32);
        q += __shfl_xor(q, 16); q += __shfl_xor(q, 32);
        if (quad == 0) { psum[wave * D + cch] = s; psq[wave * D + cch] = q; }
    }
    __syncthreads();

    int mrow = M - blockIdx.x * 64;
#pragma unroll
    for (int i = 0; i < 4; ++i) {
        int idx = (i << 8) + tid;
        int row = idx >> 4, ch8 = (idx & 15) << 3;
        if (row < mrow) {
            float4 v = *(const float4*)&sh.c[row * CT_STRIDE + ch8];
            *(float4*)(A + ((size_t)(blockIdx.x * 64 + row) << 7) + ch8) = v;
        }
    }
    if (tid < D) {
        float s = psum[tid] + psum[D + tid] + psum[2 * D + tid] + psum[3 * D + tid];
        float q = psq[tid] + psq[D + tid] + psq[2 * D + tid] + psq[3 * D + tid];
        float* st = stats_out + ((blockIdx.x & 7) << 8);
        atomicAdd(&st[tid], s);
        atomicAdd(&st[D + tid], q);
    }
}

// ---------------- BN2 + ReLU -> bf16 h, + fused weighted graph pooling -------------
__global__ __launch_bounds__(256) void k_bn2pool(
        const u16* __restrict__ y, const float* __restrict__ stats,
        const float* __restrict__ gamma, const float* __restrict__ beta,
        const int* __restrict__ gids, const float* __restrict__ fw,
        int layer, u16* __restrict__ hout, float* __restrict__ gacc,
        float invM, int M) {
    __shared__ float s_sc[D], s_sh[D];
    int t = threadIdx.x;
    if (t < D) {
        float s = 0.f, q = 0.f;
#pragma unroll
        for (int r = 0; r < 8; ++r) {
            s += stats[(r << 8) + t];
            q += stats[(r << 8) + D + t];
        }
        float mean = s * invM;
        float sv = rsqrtf(q * invM - mean * mean + 1e-5f) * gamma[t];
        s_sc[t] = sv;
        s_sh[t] = beta[t] - mean * sv;
    }
    __syncthreads();

    int c = (t & 31) << 2;
    int strip = t >> 5;
    long base = (long)blockIdx.x * 64 + (long)strip * 8;
    if (base >= M) return;
    float4 sc4 = *(const float4*)&s_sc[c];
    float4 sh4 = *(const float4*)&s_sh[c];

    ushort4 v[8];
#pragma unroll
    for (int r = 0; r < 8; ++r)
        v[r] = *(const ushort4*)(y + ((base + r) << 7) + c);
    long gmax = (long)M - 1;
    int g[8];
#pragma unroll
    for (int r = 0; r < 8; ++r) {
        long idx = base + r;
        g[r] = gids[idx > gmax ? gmax : idx];
    }

    float h0[8], h1[8], h2[8], h3[8];
#pragma unroll
    for (int r = 0; r < 8; ++r) {
        h0[r] = fmaxf(0.f, fmaf(bf2f(v[r].x), sc4.x, sh4.x));
        h1[r] = fmaxf(0.f, fmaf(bf2f(v[r].y), sc4.y, sh4.y));
        h2[r] = fmaxf(0.f, fmaf(bf2f(v[r].z), sc4.z, sh4.z));
        h3[r] = fmaxf(0.f, fmaf(bf2f(v[r].w), sc4.w, sh4.w));
    }
#pragma unroll
    for (int r = 0; r < 8; ++r) {
        if (base + r < M) {
            ushort4 o;
            o.x = f2bf(h0[r]); o.y = f2bf(h1[r]);
            o.z = f2bf(h2[r]); o.w = f2bf(h3[r]);
            *(ushort4*)(hout + ((base + r) << 7) + c) = o;
        }
    }

    float wl = fw[layer];
    int cur = -1;
    float a0 = 0.f, a1 = 0.f, a2 = 0.f, a3 = 0.f;
#pragma unroll
    for (int r = 0; r < 8; ++r) {
        if (base + r < M) {
            if (g[r] != cur) {
                if (cur >= 0) {
                    float* gp = gacc + ((size_t)cur << 7) + c;
                    atomicAdd(gp, wl * a0); atomicAdd(gp + 1, wl * a1);
                    atomicAdd(gp + 2, wl * a2); atomicAdd(gp + 3, wl * a3);
                }
                cur = g[r];
                a0 = a1 = a2 = a3 = 0.f;
            }
            a0 += h0[r]; a1 += h1[r]; a2 += h2[r]; a3 += h3[r];
        }
    }
    if (cur >= 0) {
        float* gp = gacc + ((size_t)cur << 7) + c;
        atomicAdd(gp, wl * a0); atomicAdd(gp + 1, wl * a1);
        atomicAdd(gp + 2, wl * a2); atomicAdd(gp + 3, wl * a3);
    }
}

// ---------------- final: out = gacc(Gx128) @ Wp(128x10) + bp ----------------
__global__ void k_final(const float* __restrict__ gacc, const float* __restrict__ Wp,
                        const float* __restrict__ bp, float* __restrict__ out) {
    __shared__ float w[D * DOUT];
    __shared__ float bb[DOUT];
    int t = threadIdx.x;
    for (int i = t; i < D * DOUT; i += blockDim.x) w[i] = Wp[i];
    if (t < DOUT) bb[t] = bp[t];
    __syncthreads();
    float acc[DOUT];
#pragma unroll
    for (int o = 0; o < DOUT; ++o) acc[o] = bb[o];
    for (int k = 0; k < D; ++k) {
        float a = gacc[(size_t)t * D + k];
#pragma unroll
        for (int o = 0; o < DOUT; ++o) acc[o] += a * w[k * DOUT + o];
    }
#pragma unroll
    for (int o = 0; o < DOUT; ++o) out[(size_t)t * DOUT + o] = acc[o];
}

extern "C" void kernel_launch(void* const* d_in, const int* in_sizes, int n_in,
                              void* d_out, int out_size, void* d_ws, size_t ws_size,
                              hipStream_t stream) {
    const float* x    = (const float*)d_in[0];
    const int* esrc   = (const int*)d_in[1];
    const int* edst   = (const int*)d_in[2];
    const int* gids   = (const int*)d_in[3];
    const float* eps  = (const float*)d_in[4];
    const float* fw   = (const float*)d_in[5];
    const float* W1   = (const float*)d_in[6];
    const float* b1   = (const float*)d_in[7];
    const float* g1   = (const float*)d_in[8];
    const float* bt1  = (const float*)d_in[9];
    const float* W2   = (const float*)d_in[10];
    const float* b2   = (const float*)d_in[11];
    const float* g2   = (const float*)d_in[12];
    const float* bt2  = (const float*)d_in[13];
    const float* Wp   = (const float*)d_in[14];
    const float* bp   = (const float*)d_in[15];
    float* out        = (float*)d_out;

    const int M = in_sizes[3];     // 100000 nodes
    const int E = in_sizes[1];     // 1600000 edges
    const int L = in_sizes[4];     // 4 layers
    const int G = out_size / DOUT; // 256 graphs
    const int nb  = (M + 127) >> 7;           // buckets of 128 dst nodes (782)
    const int Mpad = nb << 7;
    const int nbk = (E + 2047) >> 11;         // 2K-edge chunks (782)
    const int nbh = nb >> 1;                  // half grid for aggemm split
    const float invM = 1.0f / (float)M;

    char* ws = (char*)d_ws;
    u16* bufT  = (u16*)ws;  ws += (size_t)Mpad * D * 2;   // MLP temp bf16
    u16* bufH  = (u16*)ws;  ws += (size_t)Mpad * D * 2;   // hidden bf16
    int* pairs = (int*)ws;  ws += (size_t)nb * 4096 * 4;  // packed (src<<7)|(dst&127)
    int* cnts  = (int*)ws;  ws += (size_t)nbk * 1024 * 4; // per-(chunk,bucket) bases
    int* btot  = (int*)ws;  ws += 1024 * 4;               // bucket totals
    bf16x8* wswz = (bf16x8*)ws; ws += (size_t)2 * L * 2048 * 16;  // swizzled W
    // contiguous zero region: stats (8 replicas) | gacc
    float* stats = (float*)ws; ws += (size_t)L * 4096 * 4;
    float* gacc  = (float*)ws; ws += (size_t)G * D * 4;

    int zbytes = L * 4096 * 4 + G * D * 4;
    int n4 = zbytes / 16;
    k_zero<<<(n4 + 255) / 256, 256, 0, stream>>>((float4*)stats, n4);

    k_prepw<<<2 * L * 8, 256, 0, stream>>>(W1, W2, wswz, L);
    k_hist<<<nbk, 256, 0, stream>>>(edst, cnts, E, nb);
    k_off<<<(nb + 3) / 4, 256, 0, stream>>>(cnts, btot, nbk, nb);
    k_scat<<<nbk, 256, 0, stream>>>(esrc, edst, cnts, pairs, E, nb);
    k_cvt<<<(Mpad * (D / 4) + 255) / 256, 256, 0, stream>>>(x, bufH, M, Mpad);

    int pool_grid = (M + 63) / 64;
    for (int l = 0; l < L; ++l) {
        float* st1 = stats + (size_t)l * 4096;
        float* st2 = st1 + 2048;
        k_aggemm<<<nbh, 512, 0, stream>>>(bufH, pairs, btot, eps, l,
                                          wswz + (size_t)l * 2048, b1 + (size_t)l * D,
                                          bufT, st1, M, 0);
        k_aggemm<<<nb - nbh, 512, 0, stream>>>(bufH, pairs, btot, eps, l,
                                               wswz + (size_t)l * 2048, b1 + (size_t)l * D,
                                               bufT, st1, M, nbh);
        k_gemm_bn<<<Mpad / 64, 256, 0, stream>>>(bufT, wswz + (size_t)(L + l) * 2048,
                                                 b2 + (size_t)l * D, st1,
                                                 g1 + (size_t)l * D, bt1 + (size_t)l * D,
                                                 st2, invM, M);
        k_bn2pool<<<pool_grid, 256, 0, stream>>>(bufT, st2, g2 + (size_t)l * D,
                                                 bt2 + (size_t)l * D, gids, fw, l,
                                                 bufH, gacc, invM, M);
    }
    k_final<<<1, G, 0, stream>>>(gacc, Wp, bp, out);
}